// Round 1
// baseline (911.646 us; speedup 1.0000x reference)
//
#include <hip/hip_runtime.h>

#define G_N 40000
#define P_N 5
#define PIX 65536   // 256*256

// ---------------- sort-by-part kernels ----------------

__global__ __launch_bounds__(256) void hist_k(const int* __restrict__ part,
                                              int* __restrict__ counts, int n) {
    __shared__ int s_c[P_N];
    if (threadIdx.x < P_N) s_c[threadIdx.x] = 0;
    __syncthreads();
    int g = blockIdx.x * 256 + threadIdx.x;
    if (g < n) atomicAdd(&s_c[part[g]], 1);
    __syncthreads();
    if (threadIdx.x < P_N) atomicAdd(&counts[threadIdx.x], s_c[threadIdx.x]);
}

__global__ void offs_k(const int* __restrict__ counts, int* __restrict__ offs) {
    if (threadIdx.x == 0) {
        int o = 0;
        for (int p = 0; p < P_N; ++p) {
            offs[p] = o;
            o += (counts[p] + 31) & ~31;   // pad each part segment to 32
        }
        offs[P_N] = o;
    }
}

__global__ __launch_bounds__(256) void scatter_k(const int* __restrict__ part,
                                                 const int* __restrict__ offs,
                                                 int* __restrict__ cursors,
                                                 int* __restrict__ perm, int n) {
    const int t = threadIdx.x;
    const int g = blockIdx.x * 256 + t;
    const int p = (g < n) ? part[g] : -1;
    const int lane = t & 63;
    const int wid = t >> 6;
    __shared__ int s_wc[4][P_N];
    __shared__ int s_base[P_N];
    const unsigned long long lmask = (1ull << lane) - 1ull;
    int myrank = 0;
    for (int pp = 0; pp < P_N; ++pp) {
        unsigned long long m = __ballot(p == pp);
        if (p == pp) myrank = __popcll(m & lmask);
        if (lane == 0) s_wc[wid][pp] = __popcll(m);
    }
    __syncthreads();
    if (t < P_N) {
        int tot = s_wc[0][t] + s_wc[1][t] + s_wc[2][t] + s_wc[3][t];
        s_base[t] = atomicAdd(&cursors[t], tot);
    }
    __syncthreads();
    if (g < n) {
        int pre = 0;
        #pragma unroll
        for (int w2 = 0; w2 < 4; ++w2) if (w2 < wid) pre += s_wc[w2][p];
        perm[offs[p] + s_base[p] + pre + myrank] = g;
    }
}

// ---------------- fused MLP1+MLP2 ----------------
// block = 128 threads, 32 gaussians (all same part thanks to padded sort).
// thread j computes neuron j; x broadcast from LDS via float4 reads.

template<int DIN, int DOUT>
__device__ __forceinline__ void layerT(const float* __restrict__ w,
                                       const float* __restrict__ b,
                                       const float* xs, int xstr,
                                       float* dst, int dstr, bool act) {
    const int j = threadIdx.x;
    float acc[32];
    {
        float bj = (j < DOUT) ? b[j] : 0.f;
        #pragma unroll
        for (int g = 0; g < 32; ++g) acc[g] = bj;
    }
    if (j < DOUT) {
        constexpr int NT = DIN / 4;
        #pragma unroll 2
        for (int tk = 0; tk < NT; ++tk) {
            const int k = tk * 4;
            const float w0 = w[(k + 0) * DOUT + j];
            const float w1 = w[(k + 1) * DOUT + j];
            const float w2 = w[(k + 2) * DOUT + j];
            const float w3 = w[(k + 3) * DOUT + j];
            #pragma unroll
            for (int g = 0; g < 32; ++g) {
                const float4 xq = *(const float4*)(xs + g * xstr + k);
                float s = acc[g];
                s = fmaf(xq.x, w0, s);
                s = fmaf(xq.y, w1, s);
                s = fmaf(xq.z, w2, s);
                s = fmaf(xq.w, w3, s);
                acc[g] = s;
            }
        }
        #pragma unroll
        for (int k = NT * 4; k < DIN; ++k) {
            const float wv = w[k * DOUT + j];
            #pragma unroll
            for (int g = 0; g < 32; ++g) acc[g] = fmaf(xs[g * xstr + k], wv, acc[g]);
        }
    }
    __syncthreads();   // all reads of src buffer done before overwrite
    if (j < DOUT) {
        #pragma unroll
        for (int g = 0; g < 32; ++g) {
            float v = acc[g];
            if (act) v = fmaxf(v, 0.01f * v);   // leaky_relu(0.01)
            dst[g * dstr + j] = v;
        }
    }
    __syncthreads();
}

__global__ __launch_bounds__(128) void mlp_k(
        const float* __restrict__ latent_z, const float* __restrict__ latent_f,
        const float* __restrict__ cano,
        const float* __restrict__ w1i, const float* __restrict__ b1i,
        const float* __restrict__ w1h, const float* __restrict__ b1h,
        const float* __restrict__ w1o, const float* __restrict__ b1o,
        const float* __restrict__ w2i, const float* __restrict__ b2i,
        const float* __restrict__ w2h, const float* __restrict__ b2h,
        const float* __restrict__ w2o, const float* __restrict__ b2o,
        const int* __restrict__ uv_idx, const int* __restrict__ perm,
        const int* __restrict__ offs, const int* __restrict__ counts,
        float* __restrict__ uvmap) {
    __shared__ float s_x[32 * 112];   // x2: [96 x1][3 cano][11 attrs][2 pad]
    __shared__ float s_h[32 * 128];
    __shared__ int s_g[32];
    __shared__ int s_uv[32];

    const int t = threadIdx.x;
    const int pos0 = blockIdx.x * 32;
    if (pos0 >= offs[P_N]) return;
    int p = 0;
    #pragma unroll
    for (int q = 1; q < P_N; ++q) if (pos0 >= offs[q]) p = q;
    const int vend = offs[p] + counts[p];

    if (t < 32) {
        int pos = pos0 + t;
        int g = (pos < vend) ? perm[pos] : -1;
        s_g[t] = g;
        s_uv[t] = (g >= 0) ? uv_idx[g] : 0;
    }
    __syncthreads();

    for (int i = t; i < 32 * 96; i += 128) {
        int g = i / 96, k = i - g * 96;
        int gg = s_g[g];
        float v = 0.f;
        if (gg >= 0) v = (k < 64) ? latent_f[p * 64 + k] : latent_z[gg * 32 + (k - 64)];
        s_x[g * 112 + k] = v;
    }
    for (int i = t; i < 32 * 3; i += 128) {
        int g = i / 3, k = i - g * 3;
        int gg = s_g[g];
        s_x[g * 112 + 96 + k] = (gg >= 0) ? cano[gg * 3 + k] : 0.f;
    }
    if (t < 64) { int g = t >> 1, k = t & 1; s_x[g * 112 + 110 + k] = 0.f; }
    __syncthreads();

    // MLP1: 96 -> 128 -> 128 -> 128 -> 11 (attrs into s_x[...,99:110])
    layerT<96, 128>(w1i + p * 96 * 128, b1i + p * 128, s_x, 112, s_h, 128, true);
    layerT<128, 128>(w1h + (p * 2 + 0) * 16384, b1h + (p * 2 + 0) * 128, s_h, 128, s_h, 128, true);
    layerT<128, 128>(w1h + (p * 2 + 1) * 16384, b1h + (p * 2 + 1) * 128, s_h, 128, s_h, 128, true);
    layerT<128, 11>(w1o + p * 128 * 11, b1o + p * 11, s_h, 128, s_x + 99, 112, false);
    // MLP2: 110 -> 128 -> 128 -> 128 -> 32
    layerT<110, 128>(w2i + p * 110 * 128, b2i + p * 128, s_x, 112, s_h, 128, true);
    layerT<128, 128>(w2h + (p * 2 + 0) * 16384, b2h + (p * 2 + 0) * 128, s_h, 128, s_h, 128, true);
    layerT<128, 128>(w2h + (p * 2 + 1) * 16384, b2h + (p * 2 + 1) * 128, s_h, 128, s_h, 128, true);
    layerT<128, 32>(w2o + p * 128 * 32, b2o + p * 32, s_h, 128, s_h, 128, false);

    // scatter h[g][0:32] into channel-major uvmap  (uv_idx unique -> plain store)
    for (int i = t; i < 32 * 32; i += 128) {
        int g = i & 31, j = i >> 5;
        if (s_g[g] >= 0) uvmap[j * PIX + s_uv[g]] = s_h[g * 128 + j];
    }
}

// ---------------- CNN ----------------
// main conv: 16x16 pixel tile, 32 out-channels per block (grid.z = och half).
// thread = 1x4 pixels x 8 och. Input staged per 16-ci chunk with the
// relu / instance-norm transform of the PREVIOUS layer folded into the load.
// TRANS: 0 = raw, 1 = relu(x), 2 = relu((x-m)*rstd)

template<int CIN, int TRANS, bool STATS>
__global__ __launch_bounds__(256) void conv64_k(
        const float* __restrict__ in,    // [CIN][PIX]
        const float* __restrict__ w,     // [64][CIN][9]
        const float* __restrict__ bias,  // [64]
        const float* __restrict__ mean, const float* __restrict__ rstd,
        float* __restrict__ out,         // [64][PIX]
        float* __restrict__ ssum, float* __restrict__ ssq) {
    constexpr int CH = 16;
    __shared__ float s_in[CH][18][20];
    __shared__ float s_w[32][CH][12];

    const int tx0 = blockIdx.x * 16;
    const int ty0 = blockIdx.y * 16;
    const int och0 = blockIdx.z * 32;
    const int t = threadIdx.x;
    const int cell = t & 63;
    const int og = t >> 6;
    const int py = cell >> 2;
    const int px = (cell & 3) * 4;

    float acc[8][4];
    #pragma unroll
    for (int o = 0; o < 8; ++o)
        #pragma unroll
        for (int ox = 0; ox < 4; ++ox) acc[o][ox] = 0.f;

    for (int cc = 0; cc < CIN / CH; ++cc) {
        const int ci0 = cc * CH;
        __syncthreads();
        for (int i = t; i < CH * 324; i += 256) {
            int ci = i / 324; int rem = i - ci * 324;
            int r = rem / 18; int c = rem - r * 18;
            int gy = ty0 + r - 1, gx = tx0 + c - 1;
            float v = 0.f;
            if (gy >= 0 && gy < 256 && gx >= 0 && gx < 256) {
                v = in[(ci0 + ci) * PIX + gy * 256 + gx];
                if constexpr (TRANS == 1) v = fmaxf(v, 0.f);
                if constexpr (TRANS == 2) v = fmaxf((v - mean[ci0 + ci]) * rstd[ci0 + ci], 0.f);
            }
            s_in[ci][r][c] = v;
        }
        for (int i = t; i < 32 * CH * 9; i += 256) {
            int o = i / (CH * 9); int rem = i - o * (CH * 9);
            int ci = rem / 9; int tap = rem - ci * 9;
            s_w[o][ci][tap] = w[(och0 + o) * (CIN * 9) + (ci0 + ci) * 9 + tap];
        }
        __syncthreads();
        #pragma unroll 2
        for (int ci = 0; ci < CH; ++ci) {
            float xr[3][6];
            #pragma unroll
            for (int r = 0; r < 3; ++r) {
                const float* rp = &s_in[ci][py + r][px];
                float4 a = *(const float4*)rp;
                float2 b2 = *(const float2*)(rp + 4);
                xr[r][0] = a.x; xr[r][1] = a.y; xr[r][2] = a.z;
                xr[r][3] = a.w; xr[r][4] = b2.x; xr[r][5] = b2.y;
            }
            #pragma unroll
            for (int o = 0; o < 8; ++o) {
                const float* wp = &s_w[og * 8 + o][ci][0];
                float4 wA = *(const float4*)wp;
                float4 wB = *(const float4*)(wp + 4);
                float w8 = wp[8];
                #pragma unroll
                for (int ox = 0; ox < 4; ++ox) {
                    float s = acc[o][ox];
                    s = fmaf(xr[0][ox], wA.x, s);
                    s = fmaf(xr[0][ox + 1], wA.y, s);
                    s = fmaf(xr[0][ox + 2], wA.z, s);
                    s = fmaf(xr[1][ox], wA.w, s);
                    s = fmaf(xr[1][ox + 1], wB.x, s);
                    s = fmaf(xr[1][ox + 2], wB.y, s);
                    s = fmaf(xr[2][ox], wB.z, s);
                    s = fmaf(xr[2][ox + 1], wB.w, s);
                    s = fmaf(xr[2][ox + 2], w8, s);
                    acc[o][ox] = s;
                }
            }
        }
    }

    const int gy = ty0 + py;
    const int gx0 = tx0 + px;
    #pragma unroll
    for (int o = 0; o < 8; ++o) {
        const int och = och0 + og * 8 + o;
        const float bv = bias[och];
        float4 v;
        v.x = acc[o][0] + bv; v.y = acc[o][1] + bv;
        v.z = acc[o][2] + bv; v.w = acc[o][3] + bv;
        *(float4*)&out[och * PIX + gy * 256 + gx0] = v;
        if constexpr (STATS) {
            float s = v.x + v.y + v.z + v.w;
            float q = fmaf(v.x, v.x, fmaf(v.y, v.y, fmaf(v.z, v.z, v.w * v.w)));
            #pragma unroll
            for (int d = 32; d > 0; d >>= 1) {
                s += __shfl_down(s, d, 64);
                q += __shfl_down(q, d, 64);
            }
            if ((t & 63) == 0) {   // och is wave-uniform
                atomicAdd(&ssum[och], s);
                atomicAdd(&ssq[och], q);
            }
        }
    }
}

__global__ void stats_k(const float* __restrict__ ssum, const float* __restrict__ ssq,
                        float* __restrict__ mean, float* __restrict__ rstd) {
    int c = threadIdx.x;   // 64 threads
    float m = ssum[c] * (1.f / PIX);
    float v = ssq[c] * (1.f / PIX) - m * m;
    mean[c] = m;
    rstd[c] = rsqrtf(v + 1e-5f);
}

// conv_out: 3 channels + sigmoid, input = instance-norm (no relu).
// 16x16 tile, thread = 1x4 pixels, 4 waves split the ci range, LDS reduce.
__global__ __launch_bounds__(256) void convout_k(
        const float* __restrict__ in, const float* __restrict__ w,   // [3][64][9]
        const float* __restrict__ bias, const float* __restrict__ mean,
        const float* __restrict__ rstd, float* __restrict__ out) {
    __shared__ float s_in[16][18][20];
    __shared__ float s_w[3][16][12];
    __shared__ float s_red[256][12];

    const int tx0 = blockIdx.x * 16, ty0 = blockIdx.y * 16;
    const int t = threadIdx.x;
    const int cell = t & 63, cw = t >> 6;
    const int py = cell >> 2, px = (cell & 3) * 4;

    float acc[3][4];
    #pragma unroll
    for (int o = 0; o < 3; ++o)
        #pragma unroll
        for (int ox = 0; ox < 4; ++ox) acc[o][ox] = 0.f;

    for (int cc = 0; cc < 4; ++cc) {
        const int ci0 = cc * 16;
        __syncthreads();
        for (int i = t; i < 16 * 324; i += 256) {
            int ci = i / 324; int rem = i - ci * 324;
            int r = rem / 18; int c = rem - r * 18;
            int gy = ty0 + r - 1, gx = tx0 + c - 1;
            float v = 0.f;
            if (gy >= 0 && gy < 256 && gx >= 0 && gx < 256)
                v = (in[(ci0 + ci) * PIX + gy * 256 + gx] - mean[ci0 + ci]) * rstd[ci0 + ci];
            s_in[ci][r][c] = v;
        }
        for (int i = t; i < 3 * 144; i += 256) {
            int o = i / 144; int rem = i - o * 144;
            int ci = rem / 9; int tap = rem - ci * 9;
            s_w[o][ci][tap] = w[o * 576 + (ci0 + ci) * 9 + tap];
        }
        __syncthreads();
        #pragma unroll
        for (int cl = 0; cl < 4; ++cl) {
            const int ci = cw * 4 + cl;
            float xr[3][6];
            #pragma unroll
            for (int r = 0; r < 3; ++r) {
                const float* rp = &s_in[ci][py + r][px];
                float4 a = *(const float4*)rp;
                float2 b2 = *(const float2*)(rp + 4);
                xr[r][0] = a.x; xr[r][1] = a.y; xr[r][2] = a.z;
                xr[r][3] = a.w; xr[r][4] = b2.x; xr[r][5] = b2.y;
            }
            #pragma unroll
            for (int o = 0; o < 3; ++o) {
                const float* wp = &s_w[o][ci][0];
                float4 wA = *(const float4*)wp;
                float4 wB = *(const float4*)(wp + 4);
                float w8 = wp[8];
                #pragma unroll
                for (int ox = 0; ox < 4; ++ox) {
                    float s = acc[o][ox];
                    s = fmaf(xr[0][ox], wA.x, s);
                    s = fmaf(xr[0][ox + 1], wA.y, s);
                    s = fmaf(xr[0][ox + 2], wA.z, s);
                    s = fmaf(xr[1][ox], wA.w, s);
                    s = fmaf(xr[1][ox + 1], wB.x, s);
                    s = fmaf(xr[1][ox + 2], wB.y, s);
                    s = fmaf(xr[2][ox], wB.z, s);
                    s = fmaf(xr[2][ox + 1], wB.w, s);
                    s = fmaf(xr[2][ox + 2], w8, s);
                    acc[o][ox] = s;
                }
            }
        }
    }
    #pragma unroll
    for (int o = 0; o < 3; ++o)
        #pragma unroll
        for (int ox = 0; ox < 4; ++ox) s_red[t][o * 4 + ox] = acc[o][ox];
    __syncthreads();
    if (cw == 0) {
        #pragma unroll
        for (int w2 = 1; w2 < 4; ++w2)
            #pragma unroll
            for (int o = 0; o < 3; ++o)
                #pragma unroll
                for (int ox = 0; ox < 4; ++ox) acc[o][ox] += s_red[w2 * 64 + cell][o * 4 + ox];
        const int gy = ty0 + py, gx0 = tx0 + px;
        #pragma unroll
        for (int o = 0; o < 3; ++o) {
            float bv = bias[o];
            float4 v;
            v.x = 1.f / (1.f + __expf(-(acc[o][0] + bv)));
            v.y = 1.f / (1.f + __expf(-(acc[o][1] + bv)));
            v.z = 1.f / (1.f + __expf(-(acc[o][2] + bv)));
            v.w = 1.f / (1.f + __expf(-(acc[o][3] + bv)));
            *(float4*)&out[o * PIX + gy * 256 + gx0] = v;
        }
    }
}

// ---------------- launch ----------------

extern "C" void kernel_launch(void* const* d_in, const int* in_sizes, int n_in,
                              void* d_out, int out_size, void* d_ws, size_t ws_size,
                              hipStream_t stream) {
    (void)in_sizes; (void)n_in; (void)out_size; (void)ws_size;
    const float* latent_z = (const float*)d_in[0];
    const float* latent_f = (const float*)d_in[1];
    const float* cano     = (const float*)d_in[2];
    const float* m1wi = (const float*)d_in[3];
    const float* m1bi = (const float*)d_in[4];
    const float* m1wh = (const float*)d_in[5];
    const float* m1bh = (const float*)d_in[6];
    const float* m1wo = (const float*)d_in[7];
    const float* m1bo = (const float*)d_in[8];
    const float* m2wi = (const float*)d_in[9];
    const float* m2bi = (const float*)d_in[10];
    const float* m2wh = (const float*)d_in[11];
    const float* m2bh = (const float*)d_in[12];
    const float* m2wo = (const float*)d_in[13];
    const float* m2bo = (const float*)d_in[14];
    const float* cinw = (const float*)d_in[15];
    const float* cinb = (const float*)d_in[16];
    const float* chw  = (const float*)d_in[17];
    const float* chb  = (const float*)d_in[18];
    const float* cow  = (const float*)d_in[19];
    const float* cob  = (const float*)d_in[20];
    const int* gs_part = (const int*)d_in[21];
    const int* uv_idx  = (const int*)d_in[22];

    float* ws = (float*)d_ws;
    float* yA = ws;                         // 64*PIX
    float* yB = ws + 64 * PIX;              // 64*PIX
    float* uvmap = yB;                      // 32*PIX, aliases yB (dead after conv1 reads it)
    float* small = ws + 2 * 64 * PIX;
    int* counts  = (int*)small;             // 8
    int* cursors = counts + 8;              // 8
    int* offs    = cursors + 8;             // 8
    float* ssum  = small + 32;              // 3*64
    float* ssq   = ssum + 192;              // 3*64
    float* smean = ssq + 192;               // 3*64
    float* srstd = smean + 192;             // 3*64
    int* perm    = (int*)(srstd + 192);     // 40160

    hipMemsetAsync(uvmap, 0, (size_t)32 * PIX * sizeof(float), stream);
    hipMemsetAsync(small, 0, (32 + 2 * 192) * sizeof(float), stream);

    hist_k<<<157, 256, 0, stream>>>(gs_part, counts, G_N);
    offs_k<<<1, 64, 0, stream>>>(counts, offs);
    scatter_k<<<157, 256, 0, stream>>>(gs_part, offs, cursors, perm, G_N);
    mlp_k<<<1255, 128, 0, stream>>>(latent_z, latent_f, cano,
        m1wi, m1bi, m1wh, m1bh, m1wo, m1bo,
        m2wi, m2bi, m2wh, m2bh, m2wo, m2bo,
        uv_idx, perm, offs, counts, uvmap);

    dim3 cgrid(16, 16, 2);
    // conv_in: uvmap(=yB) -> yA, raw input, no stats
    conv64_k<32, 0, false><<<cgrid, 256, 0, stream>>>(uvmap, cinw, cinb,
        nullptr, nullptr, yA, nullptr, nullptr);
    // hidden conv 0: relu(yA) -> yB, stats slot0
    conv64_k<64, 1, true><<<cgrid, 256, 0, stream>>>(yA, chw + 0 * 36864, chb + 0,
        nullptr, nullptr, yB, ssum, ssq);
    stats_k<<<1, 64, 0, stream>>>(ssum, ssq, smean, srstd);
    // hidden conv 1: relu(IN(yB)) -> yA, stats slot1
    conv64_k<64, 2, true><<<cgrid, 256, 0, stream>>>(yB, chw + 1 * 36864, chb + 64,
        smean, srstd, yA, ssum + 64, ssq + 64);
    stats_k<<<1, 64, 0, stream>>>(ssum + 64, ssq + 64, smean + 64, srstd + 64);
    // hidden conv 2: relu(IN(yA)) -> yB, stats slot2
    conv64_k<64, 2, true><<<cgrid, 256, 0, stream>>>(yA, chw + 2 * 36864, chb + 128,
        smean + 64, srstd + 64, yB, ssum + 128, ssq + 128);
    stats_k<<<1, 64, 0, stream>>>(ssum + 128, ssq + 128, smean + 128, srstd + 128);
    // conv_out: IN(yB) (no relu) -> sigmoid -> d_out
    convout_k<<<dim3(16, 16), 256, 0, stream>>>(yB, cow, cob,
        smean + 128, srstd + 128, (float*)d_out);
}

// Round 2
// 899.829 us; speedup vs baseline: 1.0131x; 1.0131x over previous
//
#include <hip/hip_runtime.h>

#define G_N 40000
#define P_N 5
#define PIX 65536   // 256*256

// ---------------- sort-by-part kernels ----------------

__global__ __launch_bounds__(256) void hist_k(const int* __restrict__ part,
                                              int* __restrict__ counts, int n) {
    __shared__ int s_c[P_N];
    if (threadIdx.x < P_N) s_c[threadIdx.x] = 0;
    __syncthreads();
    int g = blockIdx.x * 256 + threadIdx.x;
    if (g < n) atomicAdd(&s_c[part[g]], 1);
    __syncthreads();
    if (threadIdx.x < P_N) atomicAdd(&counts[threadIdx.x], s_c[threadIdx.x]);
}

__global__ void offs_k(const int* __restrict__ counts, int* __restrict__ offs) {
    if (threadIdx.x == 0) {
        int o = 0;
        for (int p = 0; p < P_N; ++p) {
            offs[p] = o;
            o += (counts[p] + 31) & ~31;   // pad each part segment to 32 (16 | 32)
        }
        offs[P_N] = o;
    }
}

__global__ __launch_bounds__(256) void scatter_k(const int* __restrict__ part,
                                                 const int* __restrict__ offs,
                                                 int* __restrict__ cursors,
                                                 int* __restrict__ perm, int n) {
    const int t = threadIdx.x;
    const int g = blockIdx.x * 256 + t;
    const int p = (g < n) ? part[g] : -1;
    const int lane = t & 63;
    const int wid = t >> 6;
    __shared__ int s_wc[4][P_N];
    __shared__ int s_base[P_N];
    const unsigned long long lmask = (1ull << lane) - 1ull;
    int myrank = 0;
    for (int pp = 0; pp < P_N; ++pp) {
        unsigned long long m = __ballot(p == pp);
        if (p == pp) myrank = __popcll(m & lmask);
        if (lane == 0) s_wc[wid][pp] = __popcll(m);
    }
    __syncthreads();
    if (t < P_N) {
        int tot = s_wc[0][t] + s_wc[1][t] + s_wc[2][t] + s_wc[3][t];
        s_base[t] = atomicAdd(&cursors[t], tot);
    }
    __syncthreads();
    if (g < n) {
        int pre = 0;
        #pragma unroll
        for (int w2 = 0; w2 < 4; ++w2) if (w2 < wid) pre += s_wc[w2][p];
        perm[offs[p] + s_base[p] + pre + myrank] = g;
    }
}

// ---------------- weight transpose (once per launch, tiny) ----------------
// dst[p][o][k] = (k < DIN) ? src[p][k][DOUT... ] : 0   with dst rows padded to DK

__global__ __launch_bounds__(256) void transp_k(const float* __restrict__ src,
                                                float* __restrict__ dst,
                                                int DIN, int DOUT, int DK,
                                                int pps /*per-part src stride*/) {
    const int p = blockIdx.y;
    const int idx = blockIdx.x * 256 + threadIdx.x;
    const int tot = DOUT * DK;
    if (idx >= tot) return;
    const int o = idx / DK;
    const int k = idx - o * DK;
    dst[p * tot + idx] = (k < DIN) ? src[p * pps + k * DOUT + o] : 0.f;
}

// ---------------- fused MLP1+MLP2 ----------------
// block = 64 threads (1 wave), 16 gaussians, all same part (padded sort).
// layerA (DOUT=128): lane j computes neurons j and j+64 -> 8 FMAs per ds_read_b128.
// layerB (small DOUT): GRP lanes per neuron-set, 16*GRP/64 gaussians per thread.

template<int DK, int XSTR, int DSTR, bool ACT>
__device__ __forceinline__ void layerA(const float* __restrict__ wT,
                                       const float* __restrict__ b,
                                       const float* xs, float* dst) {
    const int j = threadIdx.x;      // 0..63
    float acc0[16], acc1[16];
    {
        const float b0 = b[j], b1 = b[j + 64];
        #pragma unroll
        for (int g = 0; g < 16; ++g) { acc0[g] = b0; acc1[g] = b1; }
    }
    const float* wr0 = wT + j * DK;
    const float* wr1 = wT + (j + 64) * DK;
    #pragma unroll 2
    for (int tk = 0; tk < DK / 4; ++tk) {
        const int k = tk * 4;
        const float4 wa = *(const float4*)(wr0 + k);
        const float4 wb = *(const float4*)(wr1 + k);
        #pragma unroll
        for (int g = 0; g < 16; ++g) {
            const float4 xq = *(const float4*)(xs + g * XSTR + k);
            acc0[g] = fmaf(xq.x, wa.x, fmaf(xq.y, wa.y, fmaf(xq.z, wa.z, fmaf(xq.w, wa.w, acc0[g]))));
            acc1[g] = fmaf(xq.x, wb.x, fmaf(xq.y, wb.y, fmaf(xq.z, wb.z, fmaf(xq.w, wb.w, acc1[g]))));
        }
    }
    __syncthreads();   // all reads of src done before (possibly aliasing) writes
    #pragma unroll
    for (int g = 0; g < 16; ++g) {
        float v0 = acc0[g], v1 = acc1[g];
        if (ACT) { v0 = fmaxf(v0, 0.01f * v0); v1 = fmaxf(v1, 0.01f * v1); }
        dst[g * DSTR + j] = v0;
        dst[g * DSTR + j + 64] = v1;
    }
    __syncthreads();
}

template<int DK, int GRP, int DOUT, int XSTR, int DSTR, bool ACT>
__device__ __forceinline__ void layerB(const float* __restrict__ wT,
                                       const float* __restrict__ b,
                                       const float* xs, float* dst) {
    const int j = threadIdx.x & (GRP - 1);
    const int gb = threadIdx.x / GRP;
    constexpr int NG = 16 / (64 / GRP);   // gaussians per thread
    float acc[NG];
    {
        const float bj = (j < DOUT) ? b[j] : 0.f;
        #pragma unroll
        for (int i = 0; i < NG; ++i) acc[i] = bj;
    }
    const float* wr = wT + (j < DOUT ? j : 0) * DK;
    #pragma unroll 2
    for (int tk = 0; tk < DK / 4; ++tk) {
        const int k = tk * 4;
        const float4 wv = *(const float4*)(wr + k);
        #pragma unroll
        for (int i = 0; i < NG; ++i) {
            const int g = gb * NG + i;
            const float4 xq = *(const float4*)(xs + g * XSTR + k);
            acc[i] = fmaf(xq.x, wv.x, fmaf(xq.y, wv.y, fmaf(xq.z, wv.z, fmaf(xq.w, wv.w, acc[i]))));
        }
    }
    __syncthreads();
    if (j < DOUT) {
        #pragma unroll
        for (int i = 0; i < NG; ++i) {
            float v = acc[i];
            if (ACT) v = fmaxf(v, 0.01f * v);
            dst[(gb * NG + i) * DSTR + j] = v;
        }
    }
    __syncthreads();
}

__global__ __launch_bounds__(64) void mlp_k(
        const float* __restrict__ latent_z, const float* __restrict__ latent_f,
        const float* __restrict__ cano,
        const float* __restrict__ wt1i, const float* __restrict__ b1i,
        const float* __restrict__ wt1h0, const float* __restrict__ wt1h1,
        const float* __restrict__ b1h,
        const float* __restrict__ wt1o, const float* __restrict__ b1o,
        const float* __restrict__ wt2i, const float* __restrict__ b2i,
        const float* __restrict__ wt2h0, const float* __restrict__ wt2h1,
        const float* __restrict__ b2h,
        const float* __restrict__ wt2o, const float* __restrict__ b2o,
        const int* __restrict__ uv_idx, const int* __restrict__ perm,
        const int* __restrict__ offs, const int* __restrict__ counts,
        float* __restrict__ uvmap) {
    __shared__ float s_x[16 * 112];   // [96 x1][3 cano][11 attrs][2 pad]
    __shared__ float s_h[16 * 128];
    __shared__ int s_g[16];
    __shared__ int s_uv[16];

    const int t = threadIdx.x;
    const int pos0 = blockIdx.x * 16;
    if (pos0 >= offs[P_N]) return;
    int p = 0;
    #pragma unroll
    for (int q = 1; q < P_N; ++q) if (pos0 >= offs[q]) p = q;
    const int vend = offs[p] + counts[p];

    if (t < 16) {
        const int pos = pos0 + t;
        const int g = (pos < vend) ? perm[pos] : -1;
        s_g[t] = g;
        s_uv[t] = (g >= 0) ? uv_idx[g] : 0;
    }
    __syncthreads();

    // stage x1 = [latent_f[p] (64), latent_z[g] (32)], cano (3), zero pad
    for (int i = t; i < 16 * 64; i += 64) {
        const int g = i >> 6, k = i & 63;
        s_x[g * 112 + k] = latent_f[p * 64 + k];
    }
    for (int i = t; i < 16 * 32; i += 64) {
        const int g = i >> 5, k = i & 31;
        const int gg = s_g[g];
        s_x[g * 112 + 64 + k] = (gg >= 0) ? latent_z[gg * 32 + k] : 0.f;
    }
    if (t < 48) {
        const int g = t / 3, k = t - 3 * g;
        const int gg = s_g[g];
        s_x[g * 112 + 96 + k] = (gg >= 0) ? cano[gg * 3 + k] : 0.f;
    }
    if (t < 32) { const int g = t >> 1, k = t & 1; s_x[g * 112 + 110 + k] = 0.f; }
    __syncthreads();

    // MLP1: 96 -> 128 -> 128 -> 128 -> 11 (attrs into s_x[...,99:110])
    layerA<96, 112, 128, true>(wt1i + p * 12288, b1i + p * 128, s_x, s_h);
    layerA<128, 128, 128, true>(wt1h0 + p * 16384, b1h + (p * 2 + 0) * 128, s_h, s_h);
    layerA<128, 128, 128, true>(wt1h1 + p * 16384, b1h + (p * 2 + 1) * 128, s_h, s_h);
    layerB<128, 16, 11, 128, 112, false>(wt1o + p * 1408, b1o + p * 11, s_h, s_x + 99);
    // MLP2: 110(pad 112) -> 128 -> 128 -> 128 -> 32
    layerA<112, 112, 128, true>(wt2i + p * 14336, b2i + p * 128, s_x, s_h);
    layerA<128, 128, 128, true>(wt2h0 + p * 16384, b2h + (p * 2 + 0) * 128, s_h, s_h);
    layerA<128, 128, 128, true>(wt2h1 + p * 16384, b2h + (p * 2 + 1) * 128, s_h, s_h);
    layerB<128, 32, 32, 128, 128, false>(wt2o + p * 4096, b2o + p * 32, s_h, s_h);

    // scatter h[g][0:32] into channel-major uvmap (uv_idx unique -> plain store)
    for (int i = t; i < 16 * 32; i += 64) {
        const int g = i >> 5, ch = i & 31;
        if (s_g[g] >= 0) uvmap[ch * PIX + s_uv[g]] = s_h[g * 128 + ch];
    }
}

// ---------------- CNN ----------------
// TRANS: 0 = raw, 1 = relu(x), 2 = relu((x-m)*rstd)

template<int CIN, int TRANS, bool STATS>
__global__ __launch_bounds__(256) void conv64_k(
        const float* __restrict__ in,    // [CIN][PIX]
        const float* __restrict__ w,     // [64][CIN][9]
        const float* __restrict__ bias,  // [64]
        const float* __restrict__ mean, const float* __restrict__ rstd,
        float* __restrict__ out,         // [64][PIX]
        float* __restrict__ ssum, float* __restrict__ ssq) {
    constexpr int CH = 16;
    __shared__ float s_in[CH][18][20];
    __shared__ float s_w[32][CH][12];

    const int tx0 = blockIdx.x * 16;
    const int ty0 = blockIdx.y * 16;
    const int och0 = blockIdx.z * 32;
    const int t = threadIdx.x;
    const int cell = t & 63;
    const int og = t >> 6;
    const int py = cell >> 2;
    const int px = (cell & 3) * 4;

    float acc[8][4];
    #pragma unroll
    for (int o = 0; o < 8; ++o)
        #pragma unroll
        for (int ox = 0; ox < 4; ++ox) acc[o][ox] = 0.f;

    for (int cc = 0; cc < CIN / CH; ++cc) {
        const int ci0 = cc * CH;
        __syncthreads();
        for (int i = t; i < CH * 324; i += 256) {
            int ci = i / 324; int rem = i - ci * 324;
            int r = rem / 18; int c = rem - r * 18;
            int gy = ty0 + r - 1, gx = tx0 + c - 1;
            float v = 0.f;
            if (gy >= 0 && gy < 256 && gx >= 0 && gx < 256) {
                v = in[(ci0 + ci) * PIX + gy * 256 + gx];
                if constexpr (TRANS == 1) v = fmaxf(v, 0.f);
                if constexpr (TRANS == 2) v = fmaxf((v - mean[ci0 + ci]) * rstd[ci0 + ci], 0.f);
            }
            s_in[ci][r][c] = v;
        }
        for (int i = t; i < 32 * CH * 9; i += 256) {
            int o = i / (CH * 9); int rem = i - o * (CH * 9);
            int ci = rem / 9; int tap = rem - ci * 9;
            s_w[o][ci][tap] = w[(och0 + o) * (CIN * 9) + (ci0 + ci) * 9 + tap];
        }
        __syncthreads();
        #pragma unroll 2
        for (int ci = 0; ci < CH; ++ci) {
            float xr[3][6];
            #pragma unroll
            for (int r = 0; r < 3; ++r) {
                const float* rp = &s_in[ci][py + r][px];
                float4 a = *(const float4*)rp;
                float2 b2 = *(const float2*)(rp + 4);
                xr[r][0] = a.x; xr[r][1] = a.y; xr[r][2] = a.z;
                xr[r][3] = a.w; xr[r][4] = b2.x; xr[r][5] = b2.y;
            }
            #pragma unroll
            for (int o = 0; o < 8; ++o) {
                const float* wp = &s_w[og * 8 + o][ci][0];
                float4 wA = *(const float4*)wp;
                float4 wB = *(const float4*)(wp + 4);
                float w8 = wp[8];
                #pragma unroll
                for (int ox = 0; ox < 4; ++ox) {
                    float s = acc[o][ox];
                    s = fmaf(xr[0][ox], wA.x, s);
                    s = fmaf(xr[0][ox + 1], wA.y, s);
                    s = fmaf(xr[0][ox + 2], wA.z, s);
                    s = fmaf(xr[1][ox], wA.w, s);
                    s = fmaf(xr[1][ox + 1], wB.x, s);
                    s = fmaf(xr[1][ox + 2], wB.y, s);
                    s = fmaf(xr[2][ox], wB.z, s);
                    s = fmaf(xr[2][ox + 1], wB.w, s);
                    s = fmaf(xr[2][ox + 2], w8, s);
                    acc[o][ox] = s;
                }
            }
        }
    }

    const int gy = ty0 + py;
    const int gx0 = tx0 + px;
    #pragma unroll
    for (int o = 0; o < 8; ++o) {
        const int och = och0 + og * 8 + o;
        const float bv = bias[och];
        float4 v;
        v.x = acc[o][0] + bv; v.y = acc[o][1] + bv;
        v.z = acc[o][2] + bv; v.w = acc[o][3] + bv;
        *(float4*)&out[och * PIX + gy * 256 + gx0] = v;
        if constexpr (STATS) {
            float s = v.x + v.y + v.z + v.w;
            float q = fmaf(v.x, v.x, fmaf(v.y, v.y, fmaf(v.z, v.z, v.w * v.w)));
            #pragma unroll
            for (int d = 32; d > 0; d >>= 1) {
                s += __shfl_down(s, d, 64);
                q += __shfl_down(q, d, 64);
            }
            if ((t & 63) == 0) {   // och is wave-uniform
                atomicAdd(&ssum[och], s);
                atomicAdd(&ssq[och], q);
            }
        }
    }
}

__global__ void stats_k(const float* __restrict__ ssum, const float* __restrict__ ssq,
                        float* __restrict__ mean, float* __restrict__ rstd) {
    int c = threadIdx.x;   // 64 threads
    float m = ssum[c] * (1.f / PIX);
    float v = ssq[c] * (1.f / PIX) - m * m;
    mean[c] = m;
    rstd[c] = rsqrtf(v + 1e-5f);
}

// conv_out: 3 channels + sigmoid, input = instance-norm (no relu).
__global__ __launch_bounds__(256) void convout_k(
        const float* __restrict__ in, const float* __restrict__ w,   // [3][64][9]
        const float* __restrict__ bias, const float* __restrict__ mean,
        const float* __restrict__ rstd, float* __restrict__ out) {
    __shared__ float s_in[16][18][20];
    __shared__ float s_w[3][16][12];
    __shared__ float s_red[256][12];

    const int tx0 = blockIdx.x * 16, ty0 = blockIdx.y * 16;
    const int t = threadIdx.x;
    const int cell = t & 63, cw = t >> 6;
    const int py = cell >> 2, px = (cell & 3) * 4;

    float acc[3][4];
    #pragma unroll
    for (int o = 0; o < 3; ++o)
        #pragma unroll
        for (int ox = 0; ox < 4; ++ox) acc[o][ox] = 0.f;

    for (int cc = 0; cc < 4; ++cc) {
        const int ci0 = cc * 16;
        __syncthreads();
        for (int i = t; i < 16 * 324; i += 256) {
            int ci = i / 324; int rem = i - ci * 324;
            int r = rem / 18; int c = rem - r * 18;
            int gy = ty0 + r - 1, gx = tx0 + c - 1;
            float v = 0.f;
            if (gy >= 0 && gy < 256 && gx >= 0 && gx < 256)
                v = (in[(ci0 + ci) * PIX + gy * 256 + gx] - mean[ci0 + ci]) * rstd[ci0 + ci];
            s_in[ci][r][c] = v;
        }
        for (int i = t; i < 3 * 144; i += 256) {
            int o = i / 144; int rem = i - o * 144;
            int ci = rem / 9; int tap = rem - ci * 9;
            s_w[o][ci][tap] = w[o * 576 + (ci0 + ci) * 9 + tap];
        }
        __syncthreads();
        #pragma unroll
        for (int cl = 0; cl < 4; ++cl) {
            const int ci = cw * 4 + cl;
            float xr[3][6];
            #pragma unroll
            for (int r = 0; r < 3; ++r) {
                const float* rp = &s_in[ci][py + r][px];
                float4 a = *(const float4*)rp;
                float2 b2 = *(const float2*)(rp + 4);
                xr[r][0] = a.x; xr[r][1] = a.y; xr[r][2] = a.z;
                xr[r][3] = a.w; xr[r][4] = b2.x; xr[r][5] = b2.y;
            }
            #pragma unroll
            for (int o = 0; o < 3; ++o) {
                const float* wp = &s_w[o][ci][0];
                float4 wA = *(const float4*)wp;
                float4 wB = *(const float4*)(wp + 4);
                float w8 = wp[8];
                #pragma unroll
                for (int ox = 0; ox < 4; ++ox) {
                    float s = acc[o][ox];
                    s = fmaf(xr[0][ox], wA.x, s);
                    s = fmaf(xr[0][ox + 1], wA.y, s);
                    s = fmaf(xr[0][ox + 2], wA.z, s);
                    s = fmaf(xr[1][ox], wA.w, s);
                    s = fmaf(xr[1][ox + 1], wB.x, s);
                    s = fmaf(xr[1][ox + 2], wB.y, s);
                    s = fmaf(xr[2][ox], wB.z, s);
                    s = fmaf(xr[2][ox + 1], wB.w, s);
                    s = fmaf(xr[2][ox + 2], w8, s);
                    acc[o][ox] = s;
                }
            }
        }
    }
    #pragma unroll
    for (int o = 0; o < 3; ++o)
        #pragma unroll
        for (int ox = 0; ox < 4; ++ox) s_red[t][o * 4 + ox] = acc[o][ox];
    __syncthreads();
    if (cw == 0) {
        #pragma unroll
        for (int w2 = 1; w2 < 4; ++w2)
            #pragma unroll
            for (int o = 0; o < 3; ++o)
                #pragma unroll
                for (int ox = 0; ox < 4; ++ox) acc[o][ox] += s_red[w2 * 64 + cell][o * 4 + ox];
        const int gy = ty0 + py, gx0 = tx0 + px;
        #pragma unroll
        for (int o = 0; o < 3; ++o) {
            float bv = bias[o];
            float4 v;
            v.x = 1.f / (1.f + __expf(-(acc[o][0] + bv)));
            v.y = 1.f / (1.f + __expf(-(acc[o][1] + bv)));
            v.z = 1.f / (1.f + __expf(-(acc[o][2] + bv)));
            v.w = 1.f / (1.f + __expf(-(acc[o][3] + bv)));
            *(float4*)&out[o * PIX + gy * 256 + gx0] = v;
        }
    }
}

// ---------------- launch ----------------

extern "C" void kernel_launch(void* const* d_in, const int* in_sizes, int n_in,
                              void* d_out, int out_size, void* d_ws, size_t ws_size,
                              hipStream_t stream) {
    (void)in_sizes; (void)n_in; (void)out_size; (void)ws_size;
    const float* latent_z = (const float*)d_in[0];
    const float* latent_f = (const float*)d_in[1];
    const float* cano     = (const float*)d_in[2];
    const float* m1wi = (const float*)d_in[3];
    const float* m1bi = (const float*)d_in[4];
    const float* m1wh = (const float*)d_in[5];
    const float* m1bh = (const float*)d_in[6];
    const float* m1wo = (const float*)d_in[7];
    const float* m1bo = (const float*)d_in[8];
    const float* m2wi = (const float*)d_in[9];
    const float* m2bi = (const float*)d_in[10];
    const float* m2wh = (const float*)d_in[11];
    const float* m2bh = (const float*)d_in[12];
    const float* m2wo = (const float*)d_in[13];
    const float* m2bo = (const float*)d_in[14];
    const float* cinw = (const float*)d_in[15];
    const float* cinb = (const float*)d_in[16];
    const float* chw  = (const float*)d_in[17];
    const float* chb  = (const float*)d_in[18];
    const float* cow  = (const float*)d_in[19];
    const float* cob  = (const float*)d_in[20];
    const int* gs_part = (const int*)d_in[21];
    const int* uv_idx  = (const int*)d_in[22];

    float* ws = (float*)d_ws;
    float* yA = ws;                         // 64*PIX
    float* yB = ws + 64 * PIX;              // 64*PIX
    float* uvmap = yB;                      // 32*PIX, aliases yB (dead after conv_in reads it)
    float* small = ws + 2 * 64 * PIX;
    int* counts  = (int*)small;             // 8
    int* cursors = counts + 8;              // 8
    int* offs    = cursors + 8;             // 8
    float* ssum  = small + 32;              // 3*64
    float* ssq   = ssum + 192;              // 3*64
    float* smean = ssq + 192;               // 3*64
    float* srstd = smean + 192;             // 3*64
    int* perm    = (int*)(srstd + 192);     // 40160

    // transposed weights alias yA: written before mlp_k, yA only written by conv_in (after)
    float* wt1i  = yA;                      // 5*128*96  = 61440
    float* wt1h0 = wt1i + 61440;            // 5*16384   = 81920
    float* wt1h1 = wt1h0 + 81920;           // 81920
    float* wt1o  = wt1h1 + 81920;           // 5*11*128  = 7040
    float* wt2i  = wt1o + 7040;             // 5*128*112 = 71680
    float* wt2h0 = wt2i + 71680;            // 81920
    float* wt2h1 = wt2h0 + 81920;           // 81920
    float* wt2o  = wt2h1 + 81920;           // 5*32*128  = 20480  (total 488320 < 64*PIX)

    hipMemsetAsync(uvmap, 0, (size_t)32 * PIX * sizeof(float), stream);
    hipMemsetAsync(small, 0, (32 + 2 * 192) * sizeof(float), stream);

    hist_k<<<157, 256, 0, stream>>>(gs_part, counts, G_N);
    offs_k<<<1, 64, 0, stream>>>(counts, offs);
    scatter_k<<<157, 256, 0, stream>>>(gs_part, offs, cursors, perm, G_N);

    transp_k<<<dim3(48, 5), 256, 0, stream>>>(m1wi, wt1i, 96, 128, 96, 96 * 128);
    transp_k<<<dim3(64, 5), 256, 0, stream>>>(m1wh, wt1h0, 128, 128, 128, 32768);
    transp_k<<<dim3(64, 5), 256, 0, stream>>>(m1wh + 16384, wt1h1, 128, 128, 128, 32768);
    transp_k<<<dim3(6, 5), 256, 0, stream>>>(m1wo, wt1o, 128, 11, 128, 128 * 11);
    transp_k<<<dim3(56, 5), 256, 0, stream>>>(m2wi, wt2i, 110, 128, 112, 110 * 128);
    transp_k<<<dim3(64, 5), 256, 0, stream>>>(m2wh, wt2h0, 128, 128, 128, 32768);
    transp_k<<<dim3(64, 5), 256, 0, stream>>>(m2wh + 16384, wt2h1, 128, 128, 128, 32768);
    transp_k<<<dim3(16, 5), 256, 0, stream>>>(m2wo, wt2o, 128, 32, 128, 128 * 32);

    mlp_k<<<2510, 64, 0, stream>>>(latent_z, latent_f, cano,
        wt1i, m1bi, wt1h0, wt1h1, m1bh, wt1o, m1bo,
        wt2i, m2bi, wt2h0, wt2h1, m2bh, wt2o, m2bo,
        uv_idx, perm, offs, counts, uvmap);

    dim3 cgrid(16, 16, 2);
    // conv_in: uvmap(=yB) -> yA, raw input, no stats
    conv64_k<32, 0, false><<<cgrid, 256, 0, stream>>>(uvmap, cinw, cinb,
        nullptr, nullptr, yA, nullptr, nullptr);
    // hidden conv 0: relu(yA) -> yB, stats slot0
    conv64_k<64, 1, true><<<cgrid, 256, 0, stream>>>(yA, chw + 0 * 36864, chb + 0,
        nullptr, nullptr, yB, ssum, ssq);
    stats_k<<<1, 64, 0, stream>>>(ssum, ssq, smean, srstd);
    // hidden conv 1: relu(IN(yB)) -> yA, stats slot1
    conv64_k<64, 2, true><<<cgrid, 256, 0, stream>>>(yB, chw + 1 * 36864, chb + 64,
        smean, srstd, yA, ssum + 64, ssq + 64);
    stats_k<<<1, 64, 0, stream>>>(ssum + 64, ssq + 64, smean + 64, srstd + 64);
    // hidden conv 2: relu(IN(yA)) -> yB, stats slot2
    conv64_k<64, 2, true><<<cgrid, 256, 0, stream>>>(yA, chw + 2 * 36864, chb + 128,
        smean + 64, srstd + 64, yB, ssum + 128, ssq + 128);
    stats_k<<<1, 64, 0, stream>>>(ssum + 128, ssq + 128, smean + 128, srstd + 128);
    // conv_out: IN(yB) (no relu) -> sigmoid -> d_out
    convout_k<<<dim3(16, 16), 256, 0, stream>>>(yB, cow, cob,
        smean + 128, srstd + 128, (float*)d_out);
}

// Round 3
// 358.776 us; speedup vs baseline: 2.5410x; 2.5080x over previous
//
#include <hip/hip_runtime.h>

#define G_N 40000
#define P_N 5
#define PIX 65536   // 256*256
#define XP 136      // MLP LDS activation row stride (shorts): 272B, 16B-aligned, 2-way banks
#define CIP 72      // conv LDS channel stride (shorts): 144B, 16B-aligned, 2-way banks

typedef short short8 __attribute__((ext_vector_type(8)));
typedef float f32x4 __attribute__((ext_vector_type(4)));
#define MFMA16(a, b, c) __builtin_amdgcn_mfma_f32_16x16x32_bf16(a, b, c, 0, 0, 0)

__device__ __forceinline__ short f2b(float f) {
    unsigned u = __builtin_bit_cast(unsigned, f);
    unsigned r = (u + 0x7fffu + ((u >> 16) & 1u)) >> 16;
    return (short)r;
}
__device__ __forceinline__ float b2f(short s) {
    unsigned u = ((unsigned)(unsigned short)s) << 16;
    return __builtin_bit_cast(float, u);
}

// ---------------- sort-by-part kernels ----------------

__global__ __launch_bounds__(256) void hist_k(const int* __restrict__ part,
                                              int* __restrict__ counts, int n) {
    __shared__ int s_c[P_N];
    if (threadIdx.x < P_N) s_c[threadIdx.x] = 0;
    __syncthreads();
    int g = blockIdx.x * 256 + threadIdx.x;
    if (g < n) atomicAdd(&s_c[part[g]], 1);
    __syncthreads();
    if (threadIdx.x < P_N) atomicAdd(&counts[threadIdx.x], s_c[threadIdx.x]);
}

__global__ void offs_k(const int* __restrict__ counts, int* __restrict__ offs) {
    if (threadIdx.x == 0) {
        int o = 0;
        for (int p = 0; p < P_N; ++p) {
            offs[p] = o;
            o += (counts[p] + 127) & ~127;   // pad each part segment to 128
        }
        offs[P_N] = o;
    }
}

__global__ __launch_bounds__(256) void scatter_k(const int* __restrict__ part,
                                                 const int* __restrict__ offs,
                                                 int* __restrict__ cursors,
                                                 int* __restrict__ perm, int n) {
    const int t = threadIdx.x;
    const int g = blockIdx.x * 256 + t;
    const int p = (g < n) ? part[g] : -1;
    const int lane = t & 63;
    const int wid = t >> 6;
    __shared__ int s_wc[4][P_N];
    __shared__ int s_base[P_N];
    const unsigned long long lmask = (1ull << lane) - 1ull;
    int myrank = 0;
    for (int pp = 0; pp < P_N; ++pp) {
        unsigned long long m = __ballot(p == pp);
        if (p == pp) myrank = __popcll(m & lmask);
        if (lane == 0) s_wc[wid][pp] = __popcll(m);
    }
    __syncthreads();
    if (t < P_N) {
        int tot = s_wc[0][t] + s_wc[1][t] + s_wc[2][t] + s_wc[3][t];
        s_base[t] = atomicAdd(&cursors[t], tot);
    }
    __syncthreads();
    if (g < n) {
        int pre = 0;
        #pragma unroll
        for (int w2 = 0; w2 < 4; ++w2) if (w2 < wid) pre += s_wc[w2][p];
        perm[offs[p] + s_base[p] + pre + myrank] = g;
    }
}

// ---------------- weight prep ----------------
// MLP: src fp32 [p][k(DIN)][n(DOUT)] -> dst bf16 [p][n(NP rows)][k padded to 128]
__global__ __launch_bounds__(256) void mwprep_k(const float* __restrict__ src,
                                                short* __restrict__ dst,
                                                int DIN, int DOUT, int NP, int pps) {
    const int p = blockIdx.y;
    const int idx = blockIdx.x * 256 + threadIdx.x;
    if (idx >= NP * 128) return;
    const int n = idx >> 7, k = idx & 127;
    float v = (n < DOUT && k < DIN) ? src[p * pps + k * DOUT + n] : 0.f;
    dst[p * NP * 128 + idx] = f2b(v);
}

// conv: src fp32 [l][och 64][ci CIN][tap 9] -> dst bf16 [l][tap][och][ci]
__global__ __launch_bounds__(256) void cwprep_k(const float* __restrict__ src,
                                                short* __restrict__ dst,
                                                int CIN, int NL) {
    const int idx = blockIdx.x * 256 + threadIdx.x;
    const int per = 9 * 64 * CIN;
    if (idx >= NL * per) return;
    const int l = idx / per;
    int rem = idx - l * per;
    const int tap = rem / (64 * CIN);
    rem -= tap * 64 * CIN;
    const int och = rem / CIN;
    const int ci = rem - och * CIN;
    dst[idx] = f2b(src[((l * 64 + och) * CIN + ci) * 9 + tap]);
}

// ---------------- fused MLP1+MLP2 (bf16 MFMA) ----------------
// block = 256 threads (4 waves), 128 gaussians, part-uniform (padded sort).
// Wave tile 64 g x 64 n: m0=(w>>1)*64, n0=(w&1)*64. B-frags from global (L2-hot),
// A-frags from LDS, C written back to LDS bf16.

template<int NKC, bool ACT>
__device__ __forceinline__ void dlayer(const short* __restrict__ wt, const float* __restrict__ bias,
                                       const short* src, short* dst, int m0, int n0) {
    const int lane = threadIdx.x & 63;
    const int ln = lane & 15, lq = lane >> 4;
    short8 B[4][NKC];
    float bs[4];
    #pragma unroll
    for (int nt = 0; nt < 4; ++nt) {
        #pragma unroll
        for (int kc = 0; kc < NKC; ++kc)
            B[nt][kc] = *(const short8*)(wt + (n0 + nt * 16 + ln) * 128 + kc * 32 + lq * 8);
        bs[nt] = bias[n0 + nt * 16 + ln];
    }
    #pragma unroll
    for (int mt = 0; mt < 4; ++mt) {
        short8 A[NKC];
        #pragma unroll
        for (int kc = 0; kc < NKC; ++kc)
            A[kc] = *(const short8*)(src + (m0 + mt * 16 + ln) * XP + kc * 32 + lq * 8);
        #pragma unroll
        for (int nt = 0; nt < 4; ++nt) {
            f32x4 acc = {bs[nt], bs[nt], bs[nt], bs[nt]};
            #pragma unroll
            for (int kc = 0; kc < NKC; ++kc)
                acc = MFMA16(A[kc], B[nt][kc], acc);
            #pragma unroll
            for (int r = 0; r < 4; ++r) {
                float v = acc[r];
                if (ACT) v = fmaxf(v, 0.01f * v);
                dst[(m0 + mt * 16 + lq * 4 + r) * XP + n0 + nt * 16 + ln] = f2b(v);
            }
        }
    }
}

__global__ __launch_bounds__(256) void mlp_k(
        const float* __restrict__ latent_z, const float* __restrict__ latent_f,
        const float* __restrict__ cano,
        const short* __restrict__ wt1i, const float* __restrict__ b1i,
        const short* __restrict__ wt1h0, const short* __restrict__ wt1h1,
        const float* __restrict__ b1h,
        const short* __restrict__ wt1o, const float* __restrict__ b1o,
        const short* __restrict__ wt2i, const float* __restrict__ b2i,
        const short* __restrict__ wt2h0, const short* __restrict__ wt2h1,
        const float* __restrict__ b2h,
        const short* __restrict__ wt2o, const float* __restrict__ b2o,
        const int* __restrict__ uv_idx, const int* __restrict__ perm,
        const int* __restrict__ offs, const int* __restrict__ counts,
        unsigned short* __restrict__ uvmap /* [PIX][32] bf16 */) {
    __shared__ short s_x[128 * XP];
    __shared__ short s_h0[128 * XP];
    __shared__ short s_h1[128 * XP];
    __shared__ int s_g[128];
    __shared__ int s_uv[128];

    const int t = threadIdx.x;
    const int lane = t & 63;
    const int w = t >> 6;
    const int ln = lane & 15, lq = lane >> 4;
    const int pos0 = blockIdx.x * 128;
    if (pos0 >= offs[P_N]) return;
    int p = 0;
    #pragma unroll
    for (int q = 1; q < P_N; ++q) if (pos0 >= offs[q]) p = q;
    const int vend = offs[p] + counts[p];

    if (t < 128) {
        const int pos = pos0 + t;
        const int g = (pos < vend) ? perm[pos] : -1;
        s_g[t] = g;
        s_uv[t] = (g >= 0) ? uv_idx[g] : 0;
    }
    __syncthreads();

    // stage x: k 0..63 latent_f[p], 64..95 latent_z[g], 96..98 cano, 99..135 zero
    for (int i = t; i < 128 * 64; i += 256) {
        const int g = i >> 6, k = i & 63;
        s_x[g * XP + k] = f2b(latent_f[p * 64 + k]);
    }
    for (int i = t; i < 128 * 32; i += 256) {
        const int g = i >> 5, k = i & 31;
        const int gg = s_g[g];
        s_x[g * XP + 64 + k] = (gg >= 0) ? f2b(latent_z[gg * 32 + k]) : 0;
    }
    for (int i = t; i < 128 * 3; i += 256) {
        const int g = i / 3, k = i - g * 3;
        const int gg = s_g[g];
        s_x[g * XP + 96 + k] = (gg >= 0) ? f2b(cano[gg * 3 + k]) : 0;
    }
    for (int i = t; i < 128 * 37; i += 256) {
        const int g = i / 37, k = 99 + (i - g * 37);
        s_x[g * XP + k] = 0;
    }
    __syncthreads();

    const int m0 = (w >> 1) * 64, n0 = (w & 1) * 64;

    // MLP1: 96 -> 128 -> 128 -> 128 -> 11
    dlayer<3, true>(wt1i + p * 16384, b1i + p * 128, s_x, s_h0, m0, n0);
    __syncthreads();
    dlayer<4, true>(wt1h0 + p * 16384, b1h + (p * 2 + 0) * 128, s_h0, s_h1, m0, n0);
    __syncthreads();
    dlayer<4, true>(wt1h1 + p * 16384, b1h + (p * 2 + 1) * 128, s_h1, s_h0, m0, n0);
    __syncthreads();
    // L1 out (11): waves with (w&1)==0, single n-tile, write attrs into s_x cols 99..109
    if ((w & 1) == 0) {
        short8 B[4];
        #pragma unroll
        for (int kc = 0; kc < 4; ++kc)
            B[kc] = *(const short8*)(wt1o + p * 2048 + ln * 128 + kc * 32 + lq * 8);
        const float bs = (ln < 11) ? b1o[p * 11 + ln] : 0.f;
        #pragma unroll
        for (int mt = 0; mt < 4; ++mt) {
            short8 A[4];
            #pragma unroll
            for (int kc = 0; kc < 4; ++kc)
                A[kc] = *(const short8*)(s_h0 + (m0 + mt * 16 + ln) * XP + kc * 32 + lq * 8);
            f32x4 acc = {bs, bs, bs, bs};
            #pragma unroll
            for (int kc = 0; kc < 4; ++kc) acc = MFMA16(A[kc], B[kc], acc);
            if (ln < 11) {
                #pragma unroll
                for (int r = 0; r < 4; ++r)
                    s_x[(m0 + mt * 16 + lq * 4 + r) * XP + 99 + ln] = f2b(acc[r]);
            }
        }
    }
    __syncthreads();

    // MLP2: 110(pad 128) -> 128 -> 128 -> 128 -> 32
    dlayer<4, true>(wt2i + p * 16384, b2i + p * 128, s_x, s_h0, m0, n0);
    __syncthreads();
    dlayer<4, true>(wt2h0 + p * 16384, b2h + (p * 2 + 0) * 128, s_h0, s_h1, m0, n0);
    __syncthreads();
    dlayer<4, true>(wt2h1 + p * 16384, b2h + (p * 2 + 1) * 128, s_h1, s_h0, m0, n0);
    __syncthreads();
    // L2 out (32): n-tile = (w&1), scatter to uvmap NHWC bf16
    {
        const int nt0 = (w & 1) * 16;
        short8 B[4];
        #pragma unroll
        for (int kc = 0; kc < 4; ++kc)
            B[kc] = *(const short8*)(wt2o + p * 4096 + (nt0 + ln) * 128 + kc * 32 + lq * 8);
        const float bs = b2o[p * 32 + nt0 + ln];
        #pragma unroll
        for (int mt = 0; mt < 4; ++mt) {
            short8 A[4];
            #pragma unroll
            for (int kc = 0; kc < 4; ++kc)
                A[kc] = *(const short8*)(s_h0 + (m0 + mt * 16 + ln) * XP + kc * 32 + lq * 8);
            f32x4 acc = {bs, bs, bs, bs};
            #pragma unroll
            for (int kc = 0; kc < 4; ++kc) acc = MFMA16(A[kc], B[kc], acc);
            #pragma unroll
            for (int r = 0; r < 4; ++r) {
                const int m = m0 + mt * 16 + lq * 4 + r;
                const int g = s_g[m];
                if (g >= 0)
                    uvmap[s_uv[m] * 32 + nt0 + ln] = (unsigned short)f2b(acc[r]);
            }
        }
    }
}

// ---------------- CNN (bf16 MFMA implicit GEMM, tap-decomposed) ----------------
// block = 256 threads, 16x16 pixel tile, 64 och. Wave: 4 pixel-rows x 64 och.
// TRANS: 0 raw, 1 relu, 2 IN+relu  (applied while staging input tile)

template<int CIN, int TRANS, bool STATS>
__global__ __launch_bounds__(256) void conv_k(
        const unsigned short* __restrict__ in,   // [PIX][CIN] bf16
        const short* __restrict__ wt,            // [9][64][CIN] bf16
        const float* __restrict__ bias,
        const float* __restrict__ mean, const float* __restrict__ rstd,
        unsigned short* __restrict__ out,        // [PIX][64] bf16
        float* __restrict__ ssum, float* __restrict__ ssq) {
    __shared__ short s_in[18 * 18 * CIP];
    __shared__ short s_w[2][64 * CIP];
    __shared__ float s_mr[2][64];

    const int t = threadIdx.x;
    const int lane = t & 63;
    const int w4 = t >> 6;
    const int ln = lane & 15, lq = lane >> 4;
    const int tx0 = blockIdx.x * 16, ty0 = blockIdx.y * 16;

    if (TRANS == 2 && t < 64) { s_mr[0][t] = mean[t]; s_mr[1][t] = rstd[t]; }
    __syncthreads();

    constexpr int RUNS = CIN / 8;
    for (int i = t; i < 324 * RUNS; i += 256) {
        const int sp = i / RUNS, run = i - sp * RUNS;
        const int r = sp / 18, c = sp - r * 18;
        const int gy = ty0 + r - 1, gx = tx0 + c - 1;
        short* dst = &s_in[(r * 18 + c) * CIP + run * 8];
        if (gy >= 0 && gy < 256 && gx >= 0 && gx < 256) {
            short8 v = *(const short8*)(in + ((gy * 256 + gx) * CIN + run * 8));
            if (TRANS == 0) {
                *(short8*)dst = v;
            } else {
                short8 o;
                #pragma unroll
                for (int j = 0; j < 8; ++j) {
                    float f = b2f(v[j]);
                    if (TRANS == 2) f = (f - s_mr[0][run * 8 + j]) * s_mr[1][run * 8 + j];
                    o[j] = f2b(fmaxf(f, 0.f));
                }
                *(short8*)dst = o;
            }
        } else {
            short8 z = {0, 0, 0, 0, 0, 0, 0, 0};
            *(short8*)dst = z;
        }
    }

    // weight staging (per tap, double-buffered)
    #define STAGEW(tap, buf)                                                     \
        for (int i = t; i < 64 * RUNS; i += 256) {                               \
            const int och = i / RUNS, run = i - och * RUNS;                      \
            *(short8*)&s_w[buf][och * CIP + run * 8] =                           \
                *(const short8*)(wt + ((tap) * 64 + och) * CIN + run * 8);       \
        }
    STAGEW(0, 0)
    __syncthreads();

    f32x4 acc[4][4];
    {
        float bs[4];
        #pragma unroll
        for (int nt = 0; nt < 4; ++nt) bs[nt] = bias[nt * 16 + ln];
        #pragma unroll
        for (int mt = 0; mt < 4; ++mt)
            #pragma unroll
            for (int nt = 0; nt < 4; ++nt) {
                f32x4 a = {bs[nt], bs[nt], bs[nt], bs[nt]};
                acc[mt][nt] = a;
            }
    }

    const int myrow = w4 * 4;
    for (int tap = 0; tap < 9; ++tap) {
        const int buf = tap & 1;
        if (tap + 1 < 9) { STAGEW(tap + 1, buf ^ 1) }
        const int dy = tap / 3, dx = tap % 3;
        #pragma unroll
        for (int kc = 0; kc < CIN / 32; ++kc) {
            short8 A[4], B[4];
            #pragma unroll
            for (int mt = 0; mt < 4; ++mt) {
                const int ry = myrow + mt + dy;
                const int rx = ln + dx;
                A[mt] = *(const short8*)&s_in[(ry * 18 + rx) * CIP + kc * 32 + lq * 8];
            }
            #pragma unroll
            for (int nt = 0; nt < 4; ++nt)
                B[nt] = *(const short8*)&s_w[buf][(nt * 16 + ln) * CIP + kc * 32 + lq * 8];
            #pragma unroll
            for (int mt = 0; mt < 4; ++mt)
                #pragma unroll
                for (int nt = 0; nt < 4; ++nt)
                    acc[mt][nt] = MFMA16(A[mt], B[nt], acc[mt][nt]);
        }
        __syncthreads();
    }
    #undef STAGEW

    // epilogue: store NHWC bf16 + optional per-och stats
    #pragma unroll
    for (int nt = 0; nt < 4; ++nt) {
        float lsum = 0.f, lsqs = 0.f;
        #pragma unroll
        for (int mt = 0; mt < 4; ++mt) {
            const int gy = ty0 + myrow + mt;
            #pragma unroll
            for (int r = 0; r < 4; ++r) {
                const float v = acc[mt][nt][r];
                const int gx = tx0 + lq * 4 + r;
                out[(gy * 256 + gx) * 64 + nt * 16 + ln] = (unsigned short)f2b(v);
                if (STATS) { lsum += v; lsqs = fmaf(v, v, lsqs); }
            }
        }
        if (STATS) {
            lsum += __shfl_xor(lsum, 16, 64);
            lsum += __shfl_xor(lsum, 32, 64);
            lsqs += __shfl_xor(lsqs, 16, 64);
            lsqs += __shfl_xor(lsqs, 32, 64);
            if (lq == 0) {
                atomicAdd(&ssum[nt * 16 + ln], lsum);
                atomicAdd(&ssq[nt * 16 + ln], lsqs);
            }
        }
    }
}

__global__ void stats_k(const float* __restrict__ ssum, const float* __restrict__ ssq,
                        float* __restrict__ mean, float* __restrict__ rstd) {
    const int c = threadIdx.x;   // 64 threads
    const float m = ssum[c] * (1.f / PIX);
    const float v = ssq[c] * (1.f / PIX) - m * m;
    mean[c] = m;
    rstd[c] = rsqrtf(v + 1e-5f);
}

// conv_out: 3 och + sigmoid, input = IN (no relu), fp32 VALU, output CHW fp32
__global__ __launch_bounds__(256) void convout_k(
        const unsigned short* __restrict__ in,   // [PIX][64] bf16
        const float* __restrict__ w,             // cow [3][64][3][3]
        const float* __restrict__ bias,
        const float* __restrict__ mean, const float* __restrict__ rstd,
        float* __restrict__ out) {
    __shared__ short s_in[18 * 18 * CIP];
    __shared__ float s_w[3][9][64];
    __shared__ float s_mr[2][64];

    const int t = threadIdx.x;
    const int tx0 = blockIdx.x * 16, ty0 = blockIdx.y * 16;
    if (t < 64) { s_mr[0][t] = mean[t]; s_mr[1][t] = rstd[t]; }
    __syncthreads();

    for (int i = t; i < 324 * 8; i += 256) {
        const int sp = i >> 3, run = i & 7;
        const int r = sp / 18, c = sp - r * 18;
        const int gy = ty0 + r - 1, gx = tx0 + c - 1;
        short* dst = &s_in[(r * 18 + c) * CIP + run * 8];
        if (gy >= 0 && gy < 256 && gx >= 0 && gx < 256) {
            short8 v = *(const short8*)(in + ((gy * 256 + gx) * 64 + run * 8));
            short8 o;
            #pragma unroll
            for (int j = 0; j < 8; ++j) {
                const float f = (b2f(v[j]) - s_mr[0][run * 8 + j]) * s_mr[1][run * 8 + j];
                o[j] = f2b(f);
            }
            *(short8*)dst = o;
        } else {
            short8 z = {0, 0, 0, 0, 0, 0, 0, 0};
            *(short8*)dst = z;
        }
    }
    for (int i = t; i < 1728; i += 256) {
        const int o = i / 576;
        const int rem = i - o * 576;
        const int tap = rem >> 6;
        const int ci = rem & 63;
        s_w[o][tap][ci] = w[o * 576 + ci * 9 + tap];
    }
    __syncthreads();

    const int py = t >> 4, px = t & 15;
    float a0 = bias[0], a1 = bias[1], a2 = bias[2];
    for (int tap = 0; tap < 9; ++tap) {
        const int dy = tap / 3, dx = tap % 3;
        const short* rp = &s_in[((py + dy) * 18 + (px + dx)) * CIP];
        #pragma unroll
        for (int c8 = 0; c8 < 8; ++c8) {
            short8 v = *(const short8*)(rp + c8 * 8);
            #pragma unroll
            for (int j = 0; j < 8; ++j) {
                const float f = b2f(v[j]);
                const int ci = c8 * 8 + j;
                a0 = fmaf(f, s_w[0][tap][ci], a0);
                a1 = fmaf(f, s_w[1][tap][ci], a1);
                a2 = fmaf(f, s_w[2][tap][ci], a2);
            }
        }
    }
    const int pix = (ty0 + py) * 256 + tx0 + px;
    out[pix]           = 1.f / (1.f + expf(-a0));
    out[PIX + pix]     = 1.f / (1.f + expf(-a1));
    out[2 * PIX + pix] = 1.f / (1.f + expf(-a2));
}

// ---------------- launch ----------------

extern "C" void kernel_launch(void* const* d_in, const int* in_sizes, int n_in,
                              void* d_out, int out_size, void* d_ws, size_t ws_size,
                              hipStream_t stream) {
    (void)in_sizes; (void)n_in; (void)out_size; (void)ws_size;
    const float* latent_z = (const float*)d_in[0];
    const float* latent_f = (const float*)d_in[1];
    const float* cano     = (const float*)d_in[2];
    const float* m1wi = (const float*)d_in[3];
    const float* m1bi = (const float*)d_in[4];
    const float* m1wh = (const float*)d_in[5];
    const float* m1bh = (const float*)d_in[6];
    const float* m1wo = (const float*)d_in[7];
    const float* m1bo = (const float*)d_in[8];
    const float* m2wi = (const float*)d_in[9];
    const float* m2bi = (const float*)d_in[10];
    const float* m2wh = (const float*)d_in[11];
    const float* m2bh = (const float*)d_in[12];
    const float* m2wo = (const float*)d_in[13];
    const float* m2bo = (const float*)d_in[14];
    const float* cinw = (const float*)d_in[15];
    const float* cinb = (const float*)d_in[16];
    const float* chw  = (const float*)d_in[17];
    const float* chb  = (const float*)d_in[18];
    const float* cow  = (const float*)d_in[19];
    const float* cob  = (const float*)d_in[20];
    const int* gs_part = (const int*)d_in[21];
    const int* uv_idx  = (const int*)d_in[22];

    float* ws = (float*)d_ws;
    unsigned short* actA = (unsigned short*)ws;                 // [PIX][64] bf16 = 8 MB
    unsigned short* actB = (unsigned short*)(ws + 2097152);     // [PIX][64] bf16 = 8 MB
    unsigned short* uvmap = actB;                               // [PIX][32] aliases actB head

    short* wbase = (short*)(ws + 4194304);
    short* wt1i  = wbase;               // 5*128*128 = 81920
    short* wt1h0 = wt1i  + 81920;
    short* wt1h1 = wt1h0 + 81920;
    short* wt1o  = wt1h1 + 81920;       // 5*16*128 = 10240
    short* wt2i  = wt1o  + 10240;       // 81920
    short* wt2h0 = wt2i  + 81920;
    short* wt2h1 = wt2h0 + 81920;
    short* wt2o  = wt2h1 + 81920;       // 5*32*128 = 20480
    short* cwt_in  = wt2o + 20480;      // 9*64*32  = 18432
    short* cwt_hid = cwt_in + 18432;    // 3*9*64*64 = 110592

    float* small = ws + 4194304 + 330000;   // past weight region (660 KB of shorts)
    int* counts  = (int*)small;             // 8
    int* cursors = counts + 8;              // 8
    int* offs    = cursors + 8;             // 8
    float* ssum  = small + 32;              // 3*64
    float* ssq   = ssum + 192;
    float* smean = ssq + 192;
    float* srstd = smean + 192;
    int* perm    = (int*)(srstd + 192);     // up to 40704

    hipMemsetAsync(uvmap, 0, (size_t)PIX * 32 * sizeof(unsigned short), stream);
    hipMemsetAsync(small, 0, 1024 * sizeof(float), stream);

    hist_k<<<157, 256, 0, stream>>>(gs_part, counts, G_N);
    offs_k<<<1, 64, 0, stream>>>(counts, offs);
    scatter_k<<<157, 256, 0, stream>>>(gs_part, offs, cursors, perm, G_N);

    mwprep_k<<<dim3(64, 5), 256, 0, stream>>>(m1wi, wt1i, 96, 128, 128, 96 * 128);
    mwprep_k<<<dim3(64, 5), 256, 0, stream>>>(m1wh, wt1h0, 128, 128, 128, 32768);
    mwprep_k<<<dim3(64, 5), 256, 0, stream>>>(m1wh + 16384, wt1h1, 128, 128, 128, 32768);
    mwprep_k<<<dim3(8, 5), 256, 0, stream>>>(m1wo, wt1o, 128, 11, 16, 128 * 11);
    mwprep_k<<<dim3(64, 5), 256, 0, stream>>>(m2wi, wt2i, 110, 128, 128, 110 * 128);
    mwprep_k<<<dim3(64, 5), 256, 0, stream>>>(m2wh, wt2h0, 128, 128, 128, 32768);
    mwprep_k<<<dim3(64, 5), 256, 0, stream>>>(m2wh + 16384, wt2h1, 128, 128, 128, 32768);
    mwprep_k<<<dim3(16, 5), 256, 0, stream>>>(m2wo, wt2o, 128, 32, 32, 128 * 32);
    cwprep_k<<<72, 256, 0, stream>>>(cinw, cwt_in, 32, 1);
    cwprep_k<<<432, 256, 0, stream>>>(chw, cwt_hid, 64, 3);

    mlp_k<<<318, 256, 0, stream>>>(latent_z, latent_f, cano,
        wt1i, m1bi, wt1h0, wt1h1, m1bh, wt1o, m1bo,
        wt2i, m2bi, wt2h0, wt2h1, m2bh, wt2o, m2bo,
        uv_idx, perm, offs, counts, uvmap);

    dim3 cgrid(16, 16);
    // conv_in: uvmap(raw) -> actA
    conv_k<32, 0, false><<<cgrid, 256, 0, stream>>>(uvmap, cwt_in, cinb,
        nullptr, nullptr, actA, nullptr, nullptr);
    // hidden 0: relu(actA) -> actB, stats slot0
    conv_k<64, 1, true><<<cgrid, 256, 0, stream>>>(actA, cwt_hid, chb,
        nullptr, nullptr, actB, ssum, ssq);
    stats_k<<<1, 64, 0, stream>>>(ssum, ssq, smean, srstd);
    // hidden 1: relu(IN(actB)) -> actA, stats slot1
    conv_k<64, 2, true><<<cgrid, 256, 0, stream>>>(actB, cwt_hid + 36864, chb + 64,
        smean, srstd, actA, ssum + 64, ssq + 64);
    stats_k<<<1, 64, 0, stream>>>(ssum + 64, ssq + 64, smean + 64, srstd + 64);
    // hidden 2: relu(IN(actA)) -> actB, stats slot2
    conv_k<64, 2, true><<<cgrid, 256, 0, stream>>>(actA, cwt_hid + 73728, chb + 128,
        smean + 64, srstd + 64, actB, ssum + 128, ssq + 128);
    stats_k<<<1, 64, 0, stream>>>(ssum + 128, ssq + 128, smean + 128, srstd + 128);
    // conv_out: IN(actB) -> sigmoid -> d_out (CHW fp32)
    convout_k<<<cgrid, 256, 0, stream>>>(actB, cow, cob,
        smean + 128, srstd + 128, (float*)d_out);
}

// Round 4
// 304.147 us; speedup vs baseline: 2.9974x; 1.1796x over previous
//
#include <hip/hip_runtime.h>

#define G_N 40000
#define P_N 5
#define PIX 65536   // 256*256
#define XP 136      // MLP LDS activation row stride (shorts): 272B, 16B-aligned, 2-way banks
#define CIP 72      // conv LDS channel stride (shorts): 144B, 16B-aligned, 2-way banks

typedef short short8 __attribute__((ext_vector_type(8)));
typedef short short4v __attribute__((ext_vector_type(4)));
typedef float f32x4 __attribute__((ext_vector_type(4)));
#define MFMA16(a, b, c) __builtin_amdgcn_mfma_f32_16x16x32_bf16(a, b, c, 0, 0, 0)

__device__ __forceinline__ short f2b(float f) {
    unsigned u = __builtin_bit_cast(unsigned, f);
    unsigned r = (u + 0x7fffu + ((u >> 16) & 1u)) >> 16;
    return (short)r;
}
__device__ __forceinline__ float b2f(short s) {
    unsigned u = ((unsigned)(unsigned short)s) << 16;
    return __builtin_bit_cast(float, u);
}

// ---------------- sort-by-part kernels ----------------

__global__ __launch_bounds__(256) void hist_k(const int* __restrict__ part,
                                              int* __restrict__ counts, int n) {
    __shared__ int s_c[P_N];
    if (threadIdx.x < P_N) s_c[threadIdx.x] = 0;
    __syncthreads();
    int g = blockIdx.x * 256 + threadIdx.x;
    if (g < n) atomicAdd(&s_c[part[g]], 1);
    __syncthreads();
    if (threadIdx.x < P_N) atomicAdd(&counts[threadIdx.x], s_c[threadIdx.x]);
}

__global__ void offs_k(const int* __restrict__ counts, int* __restrict__ offs) {
    if (threadIdx.x == 0) {
        int o = 0;
        for (int p = 0; p < P_N; ++p) {
            offs[p] = o;
            o += (counts[p] + 127) & ~127;   // pad each part segment to 128
        }
        offs[P_N] = o;
    }
}

__global__ __launch_bounds__(256) void scatter_k(const int* __restrict__ part,
                                                 const int* __restrict__ offs,
                                                 int* __restrict__ cursors,
                                                 int* __restrict__ perm, int n) {
    const int t = threadIdx.x;
    const int g = blockIdx.x * 256 + t;
    const int p = (g < n) ? part[g] : -1;
    const int lane = t & 63;
    const int wid = t >> 6;
    __shared__ int s_wc[4][P_N];
    __shared__ int s_base[P_N];
    const unsigned long long lmask = (1ull << lane) - 1ull;
    int myrank = 0;
    for (int pp = 0; pp < P_N; ++pp) {
        unsigned long long m = __ballot(p == pp);
        if (p == pp) myrank = __popcll(m & lmask);
        if (lane == 0) s_wc[wid][pp] = __popcll(m);
    }
    __syncthreads();
    if (t < P_N) {
        int tot = s_wc[0][t] + s_wc[1][t] + s_wc[2][t] + s_wc[3][t];
        s_base[t] = atomicAdd(&cursors[t], tot);
    }
    __syncthreads();
    if (g < n) {
        int pre = 0;
        #pragma unroll
        for (int w2 = 0; w2 < 4; ++w2) if (w2 < wid) pre += s_wc[w2][p];
        perm[offs[p] + s_base[p] + pre + myrank] = g;
    }
}

// ---------------- merged weight prep (1 launch) ----------------
// dst = wbase, segments concatenated in this exact order (element offsets):
//  wt1i@0(81920) wt1h0@81920 wt1h1@163840 wt1o@245760(10240) wt2i@256000
//  wt2h0@337920 wt2h1@419840 wt2o@501760(20480) cwt_in@522240(18432) cwt_hid@540672(110592)

__device__ __forceinline__ float mseg(int l, const float* __restrict__ src,
                                      int DIN, int DOUT, int NP, int pps) {
    const int pn = NP * 128;
    const int p = l / pn;
    const int r = l - p * pn;
    const int n = r >> 7, k = r & 127;
    return (n < DOUT && k < DIN) ? src[p * pps + k * DOUT + n] : 0.f;
}
__device__ __forceinline__ float cseg(int l, const float* __restrict__ src, int CIN) {
    const int per = 9 * 64 * CIN;
    const int ll = l / per;
    int rem = l - ll * per;
    const int tap = rem / (64 * CIN);
    rem -= tap * 64 * CIN;
    const int och = rem / CIN;
    const int ci = rem - och * CIN;
    return src[((ll * 64 + och) * CIN + ci) * 9 + tap];
}

__global__ __launch_bounds__(256) void prep_k(
        const float* __restrict__ m1wi, const float* __restrict__ m1wh,
        const float* __restrict__ m1wo, const float* __restrict__ m2wi,
        const float* __restrict__ m2wh, const float* __restrict__ m2wo,
        const float* __restrict__ cinw, const float* __restrict__ chw,
        short* __restrict__ wb) {
    const int idx = blockIdx.x * 256 + threadIdx.x;
    if (idx >= 651264) return;
    float v;
    if      (idx < 81920)  v = mseg(idx,          m1wi,         96, 128, 128, 12288);
    else if (idx < 163840) v = mseg(idx - 81920,  m1wh,        128, 128, 128, 32768);
    else if (idx < 245760) v = mseg(idx - 163840, m1wh + 16384,128, 128, 128, 32768);
    else if (idx < 256000) v = mseg(idx - 245760, m1wo,        128,  11,  16, 1408);
    else if (idx < 337920) v = mseg(idx - 256000, m2wi,        110, 128, 128, 14080);
    else if (idx < 419840) v = mseg(idx - 337920, m2wh,        128, 128, 128, 32768);
    else if (idx < 501760) v = mseg(idx - 419840, m2wh + 16384,128, 128, 128, 32768);
    else if (idx < 522240) v = mseg(idx - 501760, m2wo,        128,  32,  32, 4096);
    else if (idx < 540672) v = cseg(idx - 522240, cinw, 32);
    else                   v = cseg(idx - 540672, chw, 64);
    wb[idx] = f2b(v);
}

// ---------------- fused MLP1+MLP2 (bf16 MFMA) ----------------
// block = 256 threads (4 waves), 128 gaussians, part-uniform (padded sort).
// Wave tile 64 g x 64 n: m0=(w>>1)*64, n0=(w&1)*64. Two LDS buffers only:
// s_x (inputs+attrs, preserved) and s_h (in-place ping via A-preload trick).

template<int NKC, bool ACT>
__device__ __forceinline__ void dlayerSep(const short* __restrict__ wt,
                                          const float* __restrict__ bias,
                                          const short* src, short* dst, int m0, int n0) {
    const int lane = threadIdx.x & 63;
    const int ln = lane & 15, lq = lane >> 4;
    short8 B[4][NKC];
    float bs[4];
    #pragma unroll
    for (int nt = 0; nt < 4; ++nt) {
        #pragma unroll
        for (int kc = 0; kc < NKC; ++kc)
            B[nt][kc] = *(const short8*)(wt + (n0 + nt * 16 + ln) * 128 + kc * 32 + lq * 8);
        bs[nt] = bias[n0 + nt * 16 + ln];
    }
    #pragma unroll
    for (int mt = 0; mt < 4; ++mt) {
        short8 A[NKC];
        #pragma unroll
        for (int kc = 0; kc < NKC; ++kc)
            A[kc] = *(const short8*)(src + (m0 + mt * 16 + ln) * XP + kc * 32 + lq * 8);
        #pragma unroll
        for (int nt = 0; nt < 4; ++nt) {
            f32x4 acc = {bs[nt], bs[nt], bs[nt], bs[nt]};
            #pragma unroll
            for (int kc = 0; kc < NKC; ++kc)
                acc = MFMA16(A[kc], B[nt][kc], acc);
            #pragma unroll
            for (int r = 0; r < 4; ++r) {
                float v = acc[r];
                if (ACT) v = fmaxf(v, 0.01f * v);
                dst[(m0 + mt * 16 + lq * 4 + r) * XP + n0 + nt * 16 + ln] = f2b(v);
            }
        }
    }
}

// in-place 128->128: preload ALL A-frags, barrier, then write into same buffer
template<bool ACT>
__device__ __forceinline__ void dlayerIP(const short* __restrict__ wt,
                                         const float* __restrict__ bias,
                                         short* buf, int m0, int n0) {
    const int lane = threadIdx.x & 63;
    const int ln = lane & 15, lq = lane >> 4;
    short8 A[4][4];
    #pragma unroll
    for (int mt = 0; mt < 4; ++mt)
        #pragma unroll
        for (int kc = 0; kc < 4; ++kc)
            A[mt][kc] = *(const short8*)(buf + (m0 + mt * 16 + ln) * XP + kc * 32 + lq * 8);
    __syncthreads();   // all reads complete before any in-place write
    #pragma unroll
    for (int nt = 0; nt < 4; ++nt) {
        short8 B[4];
        #pragma unroll
        for (int kc = 0; kc < 4; ++kc)
            B[kc] = *(const short8*)(wt + (n0 + nt * 16 + ln) * 128 + kc * 32 + lq * 8);
        const float bs = bias[n0 + nt * 16 + ln];
        #pragma unroll
        for (int mt = 0; mt < 4; ++mt) {
            f32x4 acc = {bs, bs, bs, bs};
            #pragma unroll
            for (int kc = 0; kc < 4; ++kc)
                acc = MFMA16(A[mt][kc], B[kc], acc);
            #pragma unroll
            for (int r = 0; r < 4; ++r) {
                float v = acc[r];
                if (ACT) v = fmaxf(v, 0.01f * v);
                buf[(m0 + mt * 16 + lq * 4 + r) * XP + n0 + nt * 16 + ln] = f2b(v);
            }
        }
    }
    __syncthreads();
}

__global__ __launch_bounds__(256) void mlp_k(
        const float* __restrict__ latent_z, const float* __restrict__ latent_f,
        const float* __restrict__ cano,
        const short* __restrict__ wt1i, const float* __restrict__ b1i,
        const short* __restrict__ wt1h0, const short* __restrict__ wt1h1,
        const float* __restrict__ b1h,
        const short* __restrict__ wt1o, const float* __restrict__ b1o,
        const short* __restrict__ wt2i, const float* __restrict__ b2i,
        const short* __restrict__ wt2h0, const short* __restrict__ wt2h1,
        const float* __restrict__ b2h,
        const short* __restrict__ wt2o, const float* __restrict__ b2o,
        const int* __restrict__ uv_idx, const int* __restrict__ perm,
        const int* __restrict__ offs, const int* __restrict__ counts,
        unsigned short* __restrict__ uvmap /* [PIX][32] bf16 */) {
    __shared__ short s_x[128 * XP];
    __shared__ short s_h[128 * XP];
    __shared__ int s_g[128];
    __shared__ int s_uv[128];

    const int t = threadIdx.x;
    const int lane = t & 63;
    const int w = t >> 6;
    const int ln = lane & 15, lq = lane >> 4;
    const int pos0 = blockIdx.x * 128;
    if (pos0 >= offs[P_N]) return;
    int p = 0;
    #pragma unroll
    for (int q = 1; q < P_N; ++q) if (pos0 >= offs[q]) p = q;
    const int vend = offs[p] + counts[p];

    if (t < 128) {
        const int pos = pos0 + t;
        const int g = (pos < vend) ? perm[pos] : -1;
        s_g[t] = g;
        s_uv[t] = (g >= 0) ? uv_idx[g] : 0;
    }
    __syncthreads();

    // stage x: k 0..63 latent_f[p], 64..95 latent_z[g], 96..98 cano, 99..135 zero
    for (int i = t; i < 128 * 16; i += 256) {   // latent_f, float4
        const int g = i >> 4, k4 = (i & 15) * 4;
        const float4 v = *(const float4*)(latent_f + p * 64 + k4);
        short4v o = {f2b(v.x), f2b(v.y), f2b(v.z), f2b(v.w)};
        *(short4v*)(s_x + g * XP + k4) = o;
    }
    for (int i = t; i < 128 * 8; i += 256) {    // latent_z, float4
        const int g = i >> 3, k4 = (i & 7) * 4;
        const int gg = s_g[g];
        short4v o = {0, 0, 0, 0};
        if (gg >= 0) {
            const float4 v = *(const float4*)(latent_z + gg * 32 + k4);
            o[0] = f2b(v.x); o[1] = f2b(v.y); o[2] = f2b(v.z); o[3] = f2b(v.w);
        }
        *(short4v*)(s_x + g * XP + 64 + k4) = o;
    }
    for (int i = t; i < 128 * 3; i += 256) {
        const int g = i / 3, k = i - g * 3;
        const int gg = s_g[g];
        s_x[g * XP + 96 + k] = (gg >= 0) ? f2b(cano[gg * 3 + k]) : 0;
    }
    for (int i = t; i < 128 * 37; i += 256) {
        const int g = i / 37, k = 99 + (i - g * 37);
        s_x[g * XP + k] = 0;
    }
    __syncthreads();

    const int m0 = (w >> 1) * 64, n0 = (w & 1) * 64;

    // MLP1: 96 -> 128 -> 128 -> 128 -> 11
    dlayerSep<3, true>(wt1i + p * 16384, b1i + p * 128, s_x, s_h, m0, n0);
    __syncthreads();
    dlayerIP<true>(wt1h0 + p * 16384, b1h + (p * 2 + 0) * 128, s_h, m0, n0);
    dlayerIP<true>(wt1h1 + p * 16384, b1h + (p * 2 + 1) * 128, s_h, m0, n0);
    // L1 out (11): waves with (w&1)==0, write attrs into s_x cols 99..109
    if ((w & 1) == 0) {
        short8 B[4];
        #pragma unroll
        for (int kc = 0; kc < 4; ++kc)
            B[kc] = *(const short8*)(wt1o + p * 2048 + ln * 128 + kc * 32 + lq * 8);
        const float bs = (ln < 11) ? b1o[p * 11 + ln] : 0.f;
        #pragma unroll
        for (int mt = 0; mt < 4; ++mt) {
            short8 A[4];
            #pragma unroll
            for (int kc = 0; kc < 4; ++kc)
                A[kc] = *(const short8*)(s_h + (m0 + mt * 16 + ln) * XP + kc * 32 + lq * 8);
            f32x4 acc = {bs, bs, bs, bs};
            #pragma unroll
            for (int kc = 0; kc < 4; ++kc) acc = MFMA16(A[kc], B[kc], acc);
            if (ln < 11) {
                #pragma unroll
                for (int r = 0; r < 4; ++r)
                    s_x[(m0 + mt * 16 + lq * 4 + r) * XP + 99 + ln] = f2b(acc[r]);
            }
        }
    }
    __syncthreads();

    // MLP2: 110(pad 128) -> 128 -> 128 -> 128 -> 32
    dlayerSep<4, true>(wt2i + p * 16384, b2i + p * 128, s_x, s_h, m0, n0);
    __syncthreads();
    dlayerIP<true>(wt2h0 + p * 16384, b2h + (p * 2 + 0) * 128, s_h, m0, n0);
    dlayerIP<true>(wt2h1 + p * 16384, b2h + (p * 2 + 1) * 128, s_h, m0, n0);
    // L2 out (32): n-tile = (w&1), scatter to uvmap NHWC bf16
    {
        const int nt0 = (w & 1) * 16;
        short8 B[4];
        #pragma unroll
        for (int kc = 0; kc < 4; ++kc)
            B[kc] = *(const short8*)(wt2o + p * 4096 + (nt0 + ln) * 128 + kc * 32 + lq * 8);
        const float bs = b2o[p * 32 + nt0 + ln];
        #pragma unroll
        for (int mt = 0; mt < 4; ++mt) {
            short8 A[4];
            #pragma unroll
            for (int kc = 0; kc < 4; ++kc)
                A[kc] = *(const short8*)(s_h + (m0 + mt * 16 + ln) * XP + kc * 32 + lq * 8);
            f32x4 acc = {bs, bs, bs, bs};
            #pragma unroll
            for (int kc = 0; kc < 4; ++kc) acc = MFMA16(A[kc], B[kc], acc);
            #pragma unroll
            for (int r = 0; r < 4; ++r) {
                const int m = m0 + mt * 16 + lq * 4 + r;
                const int g = s_g[m];
                if (g >= 0)
                    uvmap[s_uv[m] * 32 + nt0 + ln] = (unsigned short)f2b(acc[r]);
            }
        }
    }
}

// ---------------- CNN (bf16 MFMA implicit GEMM, tap-decomposed) ----------------
// block = 256 threads, 16x16 pixel tile, 64 och. Wave: 4 pixel-rows x 64 och.
// TRANS: 0 raw, 1 relu, 2 IN+relu (mean/rstd computed in-block from ssum/ssq)

template<int CIN, int TRANS, bool STATS>
__global__ __launch_bounds__(256) void conv_k(
        const unsigned short* __restrict__ in,   // [PIX][CIN] bf16
        const short* __restrict__ wt,            // [9][64][CIN] bf16
        const float* __restrict__ bias,
        const float* __restrict__ psum, const float* __restrict__ psq,  // prev-layer stats
        unsigned short* __restrict__ out,        // [PIX][64] bf16
        float* __restrict__ ssum, float* __restrict__ ssq) {
    __shared__ short s_in[18 * 18 * CIP];
    __shared__ short s_w[2][64 * CIP];
    __shared__ float s_mr[2][64];

    const int t = threadIdx.x;
    const int lane = t & 63;
    const int w4 = t >> 6;
    const int ln = lane & 15, lq = lane >> 4;
    const int tx0 = blockIdx.x * 16, ty0 = blockIdx.y * 16;

    if (TRANS == 2 && t < 64) {
        const float m = psum[t] * (1.f / PIX);
        const float vv = psq[t] * (1.f / PIX) - m * m;
        s_mr[0][t] = m;
        s_mr[1][t] = rsqrtf(vv + 1e-5f);
    }
    __syncthreads();

    constexpr int RUNS = CIN / 8;
    for (int i = t; i < 324 * RUNS; i += 256) {
        const int sp = i / RUNS, run = i - sp * RUNS;
        const int r = sp / 18, c = sp - r * 18;
        const int gy = ty0 + r - 1, gx = tx0 + c - 1;
        short* dst = &s_in[(r * 18 + c) * CIP + run * 8];
        if (gy >= 0 && gy < 256 && gx >= 0 && gx < 256) {
            short8 v = *(const short8*)(in + ((gy * 256 + gx) * CIN + run * 8));
            if (TRANS == 0) {
                *(short8*)dst = v;
            } else {
                short8 o;
                #pragma unroll
                for (int j = 0; j < 8; ++j) {
                    float f = b2f(v[j]);
                    if (TRANS == 2) f = (f - s_mr[0][run * 8 + j]) * s_mr[1][run * 8 + j];
                    o[j] = f2b(fmaxf(f, 0.f));
                }
                *(short8*)dst = o;
            }
        } else {
            short8 z = {0, 0, 0, 0, 0, 0, 0, 0};
            *(short8*)dst = z;
        }
    }

    #define STAGEW(tap, buf)                                                     \
        for (int i = t; i < 64 * RUNS; i += 256) {                               \
            const int och = i / RUNS, run = i - och * RUNS;                      \
            *(short8*)&s_w[buf][och * CIP + run * 8] =                           \
                *(const short8*)(wt + ((tap) * 64 + och) * CIN + run * 8);       \
        }
    STAGEW(0, 0)
    __syncthreads();

    f32x4 acc[4][4];
    {
        float bs[4];
        #pragma unroll
        for (int nt = 0; nt < 4; ++nt) bs[nt] = bias[nt * 16 + ln];
        #pragma unroll
        for (int mt = 0; mt < 4; ++mt)
            #pragma unroll
            for (int nt = 0; nt < 4; ++nt) {
                f32x4 a = {bs[nt], bs[nt], bs[nt], bs[nt]};
                acc[mt][nt] = a;
            }
    }

    const int myrow = w4 * 4;
    for (int tap = 0; tap < 9; ++tap) {
        const int buf = tap & 1;
        if (tap + 1 < 9) { STAGEW(tap + 1, buf ^ 1) }
        const int dy = tap / 3, dx = tap % 3;
        #pragma unroll
        for (int kc = 0; kc < CIN / 32; ++kc) {
            short8 A[4], B[4];
            #pragma unroll
            for (int mt = 0; mt < 4; ++mt) {
                const int ry = myrow + mt + dy;
                const int rx = ln + dx;
                A[mt] = *(const short8*)&s_in[(ry * 18 + rx) * CIP + kc * 32 + lq * 8];
            }
            #pragma unroll
            for (int nt = 0; nt < 4; ++nt)
                B[nt] = *(const short8*)&s_w[buf][(nt * 16 + ln) * CIP + kc * 32 + lq * 8];
            #pragma unroll
            for (int mt = 0; mt < 4; ++mt)
                #pragma unroll
                for (int nt = 0; nt < 4; ++nt)
                    acc[mt][nt] = MFMA16(A[mt], B[nt], acc[mt][nt]);
        }
        __syncthreads();
    }
    #undef STAGEW

    #pragma unroll
    for (int nt = 0; nt < 4; ++nt) {
        float lsum = 0.f, lsqs = 0.f;
        #pragma unroll
        for (int mt = 0; mt < 4; ++mt) {
            const int gy = ty0 + myrow + mt;
            #pragma unroll
            for (int r = 0; r < 4; ++r) {
                const float v = acc[mt][nt][r];
                const int gx = tx0 + lq * 4 + r;
                out[(gy * 256 + gx) * 64 + nt * 16 + ln] = (unsigned short)f2b(v);
                if (STATS) { lsum += v; lsqs = fmaf(v, v, lsqs); }
            }
        }
        if (STATS) {
            lsum += __shfl_xor(lsum, 16, 64);
            lsum += __shfl_xor(lsum, 32, 64);
            lsqs += __shfl_xor(lsqs, 16, 64);
            lsqs += __shfl_xor(lsqs, 32, 64);
            if (lq == 0) {
                atomicAdd(&ssum[nt * 16 + ln], lsum);
                atomicAdd(&ssq[nt * 16 + ln], lsqs);
            }
        }
    }
}

// conv_out: 3 och + sigmoid, input = IN (no relu), fp32 VALU, output CHW fp32
__global__ __launch_bounds__(256) void convout_k(
        const unsigned short* __restrict__ in,   // [PIX][64] bf16
        const float* __restrict__ w,             // cow [3][64][3][3]
        const float* __restrict__ bias,
        const float* __restrict__ psum, const float* __restrict__ psq,
        float* __restrict__ out) {
    __shared__ short s_in[18 * 18 * CIP];
    __shared__ float s_w[3][9][64];
    __shared__ float s_mr[2][64];

    const int t = threadIdx.x;
    const int tx0 = blockIdx.x * 16, ty0 = blockIdx.y * 16;
    if (t < 64) {
        const float m = psum[t] * (1.f / PIX);
        const float vv = psq[t] * (1.f / PIX) - m * m;
        s_mr[0][t] = m;
        s_mr[1][t] = rsqrtf(vv + 1e-5f);
    }
    __syncthreads();

    for (int i = t; i < 324 * 8; i += 256) {
        const int sp = i >> 3, run = i & 7;
        const int r = sp / 18, c = sp - r * 18;
        const int gy = ty0 + r - 1, gx = tx0 + c - 1;
        short* dst = &s_in[(r * 18 + c) * CIP + run * 8];
        if (gy >= 0 && gy < 256 && gx >= 0 && gx < 256) {
            short8 v = *(const short8*)(in + ((gy * 256 + gx) * 64 + run * 8));
            short8 o;
            #pragma unroll
            for (int j = 0; j < 8; ++j) {
                const float f = (b2f(v[j]) - s_mr[0][run * 8 + j]) * s_mr[1][run * 8 + j];
                o[j] = f2b(f);
            }
            *(short8*)dst = o;
        } else {
            short8 z = {0, 0, 0, 0, 0, 0, 0, 0};
            *(short8*)dst = z;
        }
    }
    for (int i = t; i < 1728; i += 256) {
        const int o = i / 576;
        const int rem = i - o * 576;
        const int tap = rem >> 6;
        const int ci = rem & 63;
        s_w[o][tap][ci] = w[o * 576 + ci * 9 + tap];
    }
    __syncthreads();

    const int py = t >> 4, px = t & 15;
    float a0 = bias[0], a1 = bias[1], a2 = bias[2];
    for (int tap = 0; tap < 9; ++tap) {
        const int dy = tap / 3, dx = tap % 3;
        const short* rp = &s_in[((py + dy) * 18 + (px + dx)) * CIP];
        #pragma unroll
        for (int c8 = 0; c8 < 8; ++c8) {
            short8 v = *(const short8*)(rp + c8 * 8);
            #pragma unroll
            for (int j = 0; j < 8; ++j) {
                const float f = b2f(v[j]);
                const int ci = c8 * 8 + j;
                a0 = fmaf(f, s_w[0][tap][ci], a0);
                a1 = fmaf(f, s_w[1][tap][ci], a1);
                a2 = fmaf(f, s_w[2][tap][ci], a2);
            }
        }
    }
    const int pix = (ty0 + py) * 256 + tx0 + px;
    out[pix]           = 1.f / (1.f + expf(-a0));
    out[PIX + pix]     = 1.f / (1.f + expf(-a1));
    out[2 * PIX + pix] = 1.f / (1.f + expf(-a2));
}

// ---------------- launch ----------------

extern "C" void kernel_launch(void* const* d_in, const int* in_sizes, int n_in,
                              void* d_out, int out_size, void* d_ws, size_t ws_size,
                              hipStream_t stream) {
    (void)in_sizes; (void)n_in; (void)out_size; (void)ws_size;
    const float* latent_z = (const float*)d_in[0];
    const float* latent_f = (const float*)d_in[1];
    const float* cano     = (const float*)d_in[2];
    const float* m1wi = (const float*)d_in[3];
    const float* m1bi = (const float*)d_in[4];
    const float* m1wh = (const float*)d_in[5];
    const float* m1bh = (const float*)d_in[6];
    const float* m1wo = (const float*)d_in[7];
    const float* m1bo = (const float*)d_in[8];
    const float* m2wi = (const float*)d_in[9];
    const float* m2bi = (const float*)d_in[10];
    const float* m2wh = (const float*)d_in[11];
    const float* m2bh = (const float*)d_in[12];
    const float* m2wo = (const float*)d_in[13];
    const float* m2bo = (const float*)d_in[14];
    const float* cinw = (const float*)d_in[15];
    const float* cinb = (const float*)d_in[16];
    const float* chw  = (const float*)d_in[17];
    const float* chb  = (const float*)d_in[18];
    const float* cow  = (const float*)d_in[19];
    const float* cob  = (const float*)d_in[20];
    const int* gs_part = (const int*)d_in[21];
    const int* uv_idx  = (const int*)d_in[22];

    float* ws = (float*)d_ws;
    unsigned short* actA = (unsigned short*)ws;                 // [PIX][64] bf16 = 8 MB
    unsigned short* actB = (unsigned short*)(ws + 2097152);     // [PIX][64] bf16 = 8 MB
    unsigned short* uvmap = actB;                               // [PIX][32] aliases actB head

    short* wb = (short*)(ws + 4194304);
    short* wt1i  = wb;                  // 81920
    short* wt1h0 = wb + 81920;
    short* wt1h1 = wb + 163840;
    short* wt1o  = wb + 245760;         // 10240
    short* wt2i  = wb + 256000;
    short* wt2h0 = wb + 337920;
    short* wt2h1 = wb + 419840;
    short* wt2o  = wb + 501760;         // 20480
    short* cwt_in  = wb + 522240;       // 18432
    short* cwt_hid = wb + 540672;       // 110592 (end 651264 shorts)

    float* small = ws + 4194304 + 330000;
    int* counts  = (int*)small;             // 8
    int* cursors = counts + 8;              // 8
    int* offs    = cursors + 8;             // 8
    float* ssum  = small + 32;              // 3*64
    float* ssq   = ssum + 192;
    int* perm    = (int*)(ssq + 192);       // up to 40704

    hipMemsetAsync(uvmap, 0, (size_t)PIX * 32 * sizeof(unsigned short), stream);
    hipMemsetAsync(small, 0, 1024 * sizeof(float), stream);

    hist_k<<<157, 256, 0, stream>>>(gs_part, counts, G_N);
    offs_k<<<1, 64, 0, stream>>>(counts, offs);
    scatter_k<<<157, 256, 0, stream>>>(gs_part, offs, cursors, perm, G_N);

    prep_k<<<2544, 256, 0, stream>>>(m1wi, m1wh, m1wo, m2wi, m2wh, m2wo, cinw, chw, wb);

    mlp_k<<<318, 256, 0, stream>>>(latent_z, latent_f, cano,
        wt1i, m1bi, wt1h0, wt1h1, m1bh, wt1o, m1bo,
        wt2i, m2bi, wt2h0, wt2h1, m2bh, wt2o, m2bo,
        uv_idx, perm, offs, counts, uvmap);

    dim3 cgrid(16, 16);
    // conv_in: uvmap(raw) -> actA
    conv_k<32, 0, false><<<cgrid, 256, 0, stream>>>(uvmap, cwt_in, cinb,
        nullptr, nullptr, actA, nullptr, nullptr);
    // hidden 0: relu(actA) -> actB, stats slot0
    conv_k<64, 1, true><<<cgrid, 256, 0, stream>>>(actA, cwt_hid, chb,
        nullptr, nullptr, actB, ssum, ssq);
    // hidden 1: relu(IN(actB)) -> actA, stats slot1 (m/rstd from slot0 in-block)
    conv_k<64, 2, true><<<cgrid, 256, 0, stream>>>(actB, cwt_hid + 36864, chb + 64,
        ssum, ssq, actA, ssum + 64, ssq + 64);
    // hidden 2: relu(IN(actA)) -> actB, stats slot2
    conv_k<64, 2, true><<<cgrid, 256, 0, stream>>>(actA, cwt_hid + 73728, chb + 128,
        ssum + 64, ssq + 64, actB, ssum + 128, ssq + 128);
    // conv_out: IN(actB) -> sigmoid -> d_out (CHW fp32)
    convout_k<<<cgrid, 256, 0, stream>>>(actB, cow, cob,
        ssum + 128, ssq + 128, (float*)d_out);
}